// Round 3
// baseline (5500.869 us; speedup 1.0000x reference)
//
#include <hip/hip_runtime.h>
#include <math.h>

#define NN 50000
#define NE 300000

static constexpr int TN = 16;

// ---------------- lin1: h1 = relu(x @ W(3,16) + b) ----------------
__global__ void lin1_kernel(const float* __restrict__ x,
                            const float* __restrict__ w,
                            const float* __restrict__ b,
                            float* __restrict__ out) {
    int idx = blockIdx.x * 256 + threadIdx.x;
    if (idx >= NN * 16) return;
    int n = idx >> 4, o = idx & 15;
    float v = x[n*3+0]*w[o] + x[n*3+1]*w[16+o] + x[n*3+2]*w[32+o] + b[o];
    out[idx] = fmaxf(v, 0.f);
}

// ---------------- a = h @ u  (N x 8 attention projections) ----------------
template<int CIN>
__global__ void a_kernel(const float* __restrict__ h,
                         const float* __restrict__ u,
                         float* __restrict__ a) {
    int idx = blockIdx.x * 256 + threadIdx.x;
    if (idx >= NN * 8) return;
    int n = idx >> 3, hd = idx & 7;
    float acc = 0.f;
    #pragma unroll
    for (int k = 0; k < CIN; ++k) acc += h[(size_t)n*CIN + k] * u[k*8 + hd];
    a[idx] = acc;
}

// ---------------- sc = softmax(c) (self-loop attention, node-uniform) -----
__global__ void sc_kernel(const float* __restrict__ c, float* __restrict__ sc) {
    float m = c[0];
    for (int h = 1; h < 8; ++h) m = fmaxf(m, c[h]);
    float s = 0.f; float e[8];
    for (int h = 0; h < 8; ++h) { e[h] = expf(c[h] - m); s += e[h]; }
    for (int h = 0; h < 8; ++h) sc[h] = e[h] / s;
}

// ---------------- proj chunk: yc[n][h][oc] = h[n] @ W[:, h*O + o0 + oc] ---
template<int CIN>
__global__ __launch_bounds__(256) void proj_kernel(
        const float* __restrict__ h, const float* __restrict__ W,
        float* __restrict__ yc, int HC, int O, int o0, int OC) {
    __shared__ float hs[TN][CIN];
    const int tid = threadIdx.x;
    const int cols = 8 * OC;
    const int hd = tid / OC, oc = tid % OC;
    float wreg[CIN];
    if (tid < cols) {
        int wcol = hd * O + o0 + oc;
        #pragma unroll
        for (int k = 0; k < CIN; ++k) wreg[k] = W[k*HC + wcol];
    } else {
        #pragma unroll
        for (int k = 0; k < CIN; ++k) wreg[k] = 0.f;
    }
    for (int n0 = blockIdx.y * TN; n0 < NN; n0 += gridDim.y * TN) {
        __syncthreads();
        for (int i = tid; i < TN * CIN; i += 256) {
            int t = i / CIN, k = i % CIN;
            int n = n0 + t;
            hs[t][k] = (n < NN) ? h[(size_t)n*CIN + k] : 0.f;
        }
        __syncthreads();
        if (tid < cols) {
            float acc[TN];
            #pragma unroll
            for (int t = 0; t < TN; ++t) acc[t] = 0.f;
            #pragma unroll
            for (int k = 0; k < CIN; k += 4) {
                #pragma unroll
                for (int t = 0; t < TN; ++t) {
                    float4 hv = *(const float4*)&hs[t][k];
                    acc[t] += hv.x*wreg[k+0] + hv.y*wreg[k+1]
                            + hv.z*wreg[k+2] + hv.w*wreg[k+3];
                }
            }
            #pragma unroll
            for (int t = 0; t < TN; ++t)
                if (n0 + t < NN) yc[(size_t)(n0+t)*cols + tid] = acc[t];
        }
    }
}

// ---------------- q: per-edge head softmax of a[s]-a[d]+c ----------------
__global__ void q_kernel(const int* __restrict__ src,
                         const int* __restrict__ dst,
                         const float* __restrict__ a,
                         const float* __restrict__ c,
                         float* __restrict__ q) {
    int e = blockIdx.x * 256 + threadIdx.x;
    if (e >= NE) return;
    int s = src[e], d = dst[e];
    const float4* as = (const float4*)(a + (size_t)s*8);
    const float4* ad = (const float4*)(a + (size_t)d*8);
    float4 s0 = as[0], s1 = as[1], d0 = ad[0], d1 = ad[1];
    float lg[8] = { s0.x-d0.x+c[0], s0.y-d0.y+c[1], s0.z-d0.z+c[2], s0.w-d0.w+c[3],
                    s1.x-d1.x+c[4], s1.y-d1.y+c[5], s1.z-d1.z+c[6], s1.w-d1.w+c[7] };
    float m = lg[0];
    #pragma unroll
    for (int h = 1; h < 8; ++h) m = fmaxf(m, lg[h]);
    float sum = 0.f;
    #pragma unroll
    for (int h = 0; h < 8; ++h) { lg[h] = expf(lg[h]-m); sum += lg[h]; }
    float inv = 1.f / sum;
    float4* qp = (float4*)(q + (size_t)e*8);
    qp[0] = make_float4(lg[0]*inv, lg[1]*inv, lg[2]*inv, lg[3]*inv);
    qp[1] = make_float4(lg[4]*inv, lg[5]*inv, lg[6]*inv, lg[7]*inv);
}

// ---------------- self-loop add: agg[n, o0+oc] += sum_h sc[h]*yc[n][h][oc] -
__global__ void self_kernel(const float* __restrict__ yc,
                            const float* __restrict__ sc,
                            float* __restrict__ agg,
                            int O, int o0, int oc_sh) {
    int OC = 1 << oc_sh;
    int idx = blockIdx.x * 256 + threadIdx.x;
    if (idx >= NN * OC) return;
    int n = idx >> oc_sh, oc = idx & (OC - 1);
    float v = 0.f;
    #pragma unroll
    for (int h = 0; h < 8; ++h) v += sc[h] * yc[(size_t)n*(8*OC) + h*OC + oc];
    agg[(size_t)n*O + o0 + oc] += v;
}

// ---------------- msg chunk: agg[d, o0..o0+OC) += sum_h q[e,h]*yc[s][h][..]
__global__ void msg_kernel(const int* __restrict__ src,
                           const int* __restrict__ dst,
                           const float* __restrict__ q,
                           const float* __restrict__ yc,
                           float* __restrict__ agg,
                           int O, int o0, int tpe_sh) {
    int gid = blockIdx.x * 256 + threadIdx.x;
    int e = gid >> tpe_sh;
    if (e >= NE) return;
    int lane = gid & ((1 << tpe_sh) - 1);
    int oc4 = 1 << tpe_sh;              // OC/4
    int s = src[e], d = dst[e];
    const float4* yr = (const float4*)(yc + (size_t)s * (oc4 << 5));  // 8*OC floats
    const float4* qp = (const float4*)(q + (size_t)e * 8);
    float4 q0 = qp[0], q1 = qp[1];
    float qh[8] = {q0.x, q0.y, q0.z, q0.w, q1.x, q1.y, q1.z, q1.w};
    float4 acc = make_float4(0.f, 0.f, 0.f, 0.f);
    #pragma unroll
    for (int h = 0; h < 8; ++h) {
        float4 v = yr[h*oc4 + lane];
        acc.x += qh[h]*v.x; acc.y += qh[h]*v.y;
        acc.z += qh[h]*v.z; acc.w += qh[h]*v.w;
    }
    float* ag = agg + (size_t)d*O + o0 + (lane << 2);
    atomicAdd(ag+0, acc.x); atomicAdd(ag+1, acc.y);
    atomicAdd(ag+2, acc.z); atomicAdd(ag+3, acc.w);
}

// ---------------- finalize: out = relu(agg/cnt + b) ----------------
__global__ void finalize_kernel(const float* __restrict__ agg,
                                const float* __restrict__ cnt,
                                const float* __restrict__ b,
                                float* __restrict__ out, int o_sh) {
    int O = 1 << o_sh;
    int idx = blockIdx.x * 256 + threadIdx.x;
    if (idx >= NN * O) return;
    int n = idx >> o_sh, o = idx & (O - 1);
    out[idx] = fmaxf(agg[idx] / cnt[n] + b[o], 0.f);
}

// ---------------- degree ----------------
__global__ void cnt_init_kernel(float* cnt) {
    int n = blockIdx.x * 256 + threadIdx.x;
    if (n < NN) cnt[n] = 1.0f;   // self loop
}
__global__ void indeg_kernel(const int* __restrict__ dst, float* cnt) {
    int e = blockIdx.x * 256 + threadIdx.x;
    if (e < NE) atomicAdd(&cnt[dst[e]], 1.0f);
}

// ---------------- fused lin2(relu) + lin3 + sigmoid ----------------
__global__ __launch_bounds__(256) void lin23_kernel(
        const float* __restrict__ h, const float* __restrict__ w2,
        const float* __restrict__ b2, const float* __restrict__ w3,
        const float* __restrict__ b3, float* __restrict__ p) {
    __shared__ float hs[16][128];
    __shared__ float red[4*16];
    const int tid = threadIdx.x;
    const int n0 = blockIdx.x * 16;
    for (int i = tid; i < 16*128; i += 256) {
        int t = i >> 7, k = i & 127;
        hs[t][k] = (n0 + t < NN) ? h[(size_t)(n0+t)*128 + k] : 0.f;
    }
    __syncthreads();
    float part[16];
    #pragma unroll
    for (int t = 0; t < 16; ++t) part[t] = 0.f;
    for (int cc = 0; cc < 4; ++cc) {
        int col = tid + cc*256;
        float acc[16];
        float bb = b2[col];
        #pragma unroll
        for (int t = 0; t < 16; ++t) acc[t] = bb;
        for (int k = 0; k < 128; k += 4) {
            float wa = w2[(size_t)(k+0)*1024 + col];
            float wb = w2[(size_t)(k+1)*1024 + col];
            float wc = w2[(size_t)(k+2)*1024 + col];
            float wd = w2[(size_t)(k+3)*1024 + col];
            #pragma unroll
            for (int t = 0; t < 16; ++t) {
                float4 hv = *(const float4*)&hs[t][k];
                acc[t] += hv.x*wa + hv.y*wb + hv.z*wc + hv.w*wd;
            }
        }
        float w3c = w3[col];
        #pragma unroll
        for (int t = 0; t < 16; ++t) part[t] += fmaxf(acc[t], 0.f) * w3c;
    }
    #pragma unroll
    for (int t = 0; t < 16; ++t) {
        float v = part[t];
        #pragma unroll
        for (int off = 32; off; off >>= 1) v += __shfl_down(v, off, 64);
        if ((tid & 63) == 0) red[(tid >> 6)*16 + t] = v;
    }
    __syncthreads();
    if (tid < 16) {
        int n = n0 + tid;
        if (n < NN) {
            float z = red[tid] + red[16+tid] + red[32+tid] + red[48+tid] + b3[0];
            p[n] = 1.f / (1.f + expf(-z));
        }
    }
}

// ---------------- loss ----------------
__global__ void loss_pass_kernel(const float* __restrict__ labels,
                                 const float* __restrict__ p,
                                 float* __restrict__ scal) {
    __shared__ float sh0[256], sh1[256], sh2[256];
    int tid = threadIdx.x;
    float pos = 0.f, sp = 0.f, sn = 0.f;
    for (int n = blockIdx.x*256 + tid; n < NN; n += gridDim.x*256) {
        float yv = labels[n], pv = p[n];
        if (yv == 1.0f) { pos += 1.f; sp -= fmaxf(logf(pv), -100.f); }
        else            { sn -= fmaxf(logf(1.f - pv), -100.f); }
    }
    sh0[tid] = pos; sh1[tid] = sp; sh2[tid] = sn;
    __syncthreads();
    for (int off = 128; off; off >>= 1) {
        if (tid < off) {
            sh0[tid] += sh0[tid+off];
            sh1[tid] += sh1[tid+off];
            sh2[tid] += sh2[tid+off];
        }
        __syncthreads();
    }
    if (tid == 0) {
        atomicAdd(&scal[0], sh0[0]);
        atomicAdd(&scal[1], sh1[0]);
        atomicAdd(&scal[2], sh2[0]);
    }
}

__global__ void loss_final_kernel(const float* __restrict__ scal,
                                  float* __restrict__ out) {
    float pos = scal[0];
    out[0] = scal[1] / (2.f*pos) + scal[2] / (2.f*((float)NN - pos));
}

// ---------------- launch ----------------
extern "C" void kernel_launch(void* const* d_in, const int* in_sizes, int n_in,
                              void* d_out, int out_size, void* d_ws, size_t ws_size,
                              hipStream_t stream) {
    (void)in_sizes; (void)n_in; (void)out_size;
    const float* x   = (const float*)d_in[0];
    const int*   ei  = (const int*)d_in[1];      // int32 per harness contract
    const float* labels = (const float*)d_in[2];
    const float* l1w = (const float*)d_in[3];
    const float* l1b = (const float*)d_in[4];
    const float* cw[3] = {(const float*)d_in[5], (const float*)d_in[9],  (const float*)d_in[13]};
    const float* cu[3] = {(const float*)d_in[6], (const float*)d_in[10], (const float*)d_in[14]};
    const float* cc[3] = {(const float*)d_in[7], (const float*)d_in[11], (const float*)d_in[15]};
    const float* cb[3] = {(const float*)d_in[8], (const float*)d_in[12], (const float*)d_in[16]};
    const float* l2w = (const float*)d_in[17];
    const float* l2b = (const float*)d_in[18];
    const float* l3w = (const float*)d_in[19];
    const float* l3b = (const float*)d_in[20];
    const int* srcp = ei;
    const int* dstp = ei + NE;
    float* out = (float*)d_out;

    // ---- workspace layout (16-float aligned blocks) ----
    float* ws = (float*)d_ws;
    size_t off = 0;
    auto alloc = [&](size_t n) { float* p = ws + off; off += (n + 15) & ~(size_t)15; return p; };
    float* h1   = alloc((size_t)NN*16);
    float* h2   = alloc((size_t)NN*32);
    float* h3   = alloc((size_t)NN*64);
    float* h4   = alloc((size_t)NN*128);
    float* a    = alloc((size_t)NN*8);
    float* q    = alloc((size_t)NE*8);
    float* agg  = alloc((size_t)NN*128);
    float* cnt  = alloc((size_t)NN);
    float* scal = alloc(16);
    float* sc   = alloc(16);
    // adaptive chunk width for the projected-feature buffer yc (N x 8 x OC)
    int oc_sh = 3;                                               // OC = 8
    if ((off + (size_t)NN*8*32) * 4 <= ws_size) oc_sh = 5;       // OC = 32
    else if ((off + (size_t)NN*8*16) * 4 <= ws_size) oc_sh = 4;  // OC = 16
    const int OC = 1 << oc_sh;
    float* yc = ws + off;

    // ---- degree (layer-independent) + scalar zero ----
    cnt_init_kernel<<<(NN+255)/256, 256, 0, stream>>>(cnt);
    indeg_kernel<<<(NE+255)/256, 256, 0, stream>>>(dstp, cnt);
    hipMemsetAsync(scal, 0, 16*sizeof(float), stream);

    // ---- lin1 ----
    lin1_kernel<<<(NN*16+255)/256, 256, 0, stream>>>(x, l1w, l1b, h1);

    // ---- three FeaStConv layers ----
    const float* hin_arr[3]  = {h1, h2, h3};
    float*       hout_arr[3] = {h2, h3, h4};
    const int    cin_arr[3]  = {16, 32, 64};
    const int    osh_arr[3]  = {5, 6, 7};     // O = 32, 64, 128

    for (int L = 0; L < 3; ++L) {
        const float* hin = hin_arr[L];
        float* hout = hout_arr[L];
        const int O = 1 << osh_arr[L];
        const int HC = 8 * O;

        if (cin_arr[L] == 16)      a_kernel<16><<<(NN*8+255)/256, 256, 0, stream>>>(hin, cu[L], a);
        else if (cin_arr[L] == 32) a_kernel<32><<<(NN*8+255)/256, 256, 0, stream>>>(hin, cu[L], a);
        else                       a_kernel<64><<<(NN*8+255)/256, 256, 0, stream>>>(hin, cu[L], a);
        sc_kernel<<<1, 1, 0, stream>>>(cc[L], sc);
        q_kernel<<<(NE+255)/256, 256, 0, stream>>>(srcp, dstp, a, cc[L], q);
        hipMemsetAsync(agg, 0, (size_t)NN*O*sizeof(float), stream);

        const int nchunk = O / OC;
        const int tpe_sh = oc_sh - 2;    // OC/4 threads per edge
        for (int ch = 0; ch < nchunk; ++ch) {
            const int o0 = ch * OC;
            if (cin_arr[L] == 16)
                proj_kernel<16><<<dim3(1,192), 256, 0, stream>>>(hin, cw[L], yc, HC, O, o0, OC);
            else if (cin_arr[L] == 32)
                proj_kernel<32><<<dim3(1,192), 256, 0, stream>>>(hin, cw[L], yc, HC, O, o0, OC);
            else
                proj_kernel<64><<<dim3(1,192), 256, 0, stream>>>(hin, cw[L], yc, HC, O, o0, OC);
            self_kernel<<<((size_t)NN*OC+255)/256, 256, 0, stream>>>(yc, sc, agg, O, o0, oc_sh);
            msg_kernel<<<(((size_t)NE<<tpe_sh)+255)/256, 256, 0, stream>>>(srcp, dstp, q, yc, agg, O, o0, tpe_sh);
        }
        finalize_kernel<<<((size_t)NN*O+255)/256, 256, 0, stream>>>(agg, cnt, cb[L], hout, osh_arr[L]);
    }

    // ---- fused lin2 + relu + lin3 + sigmoid -> p ----
    lin23_kernel<<<(NN+15)/16, 256, 0, stream>>>(h4, l2w, l2b, l3w, l3b, out + 1);

    // ---- class-balanced BCE loss ----
    loss_pass_kernel<<<256, 256, 0, stream>>>(labels, out + 1, scal);
    loss_final_kernel<<<1, 1, 0, stream>>>(scal, out);
}

// Round 4
// 1611.261 us; speedup vs baseline: 3.4140x; 3.4140x over previous
//
#include <hip/hip_runtime.h>
#include <math.h>

#define NN 50000
#define NE 300000

static constexpr int TN = 16;   // nodes per proj tile; NN % TN == 0

// ---------------- lin1: h1 = relu(x @ W(3,16) + b) ----------------
__global__ void lin1_kernel(const float* __restrict__ x,
                            const float* __restrict__ w,
                            const float* __restrict__ b,
                            float* __restrict__ out) {
    int idx = blockIdx.x * 256 + threadIdx.x;
    if (idx >= NN * 16) return;
    int n = idx >> 4, o = idx & 15;
    float v = x[n*3+0]*w[o] + x[n*3+1]*w[16+o] + x[n*3+2]*w[32+o] + b[o];
    out[idx] = fmaxf(v, 0.f);
}

// ---------------- a = h @ u  (N x 8 attention projections) ----------------
template<int CIN>
__global__ void a_kernel(const float* __restrict__ h,
                         const float* __restrict__ u,
                         float* __restrict__ a) {
    int idx = blockIdx.x * 256 + threadIdx.x;
    if (idx >= NN * 8) return;
    int n = idx >> 3, hd = idx & 7;
    float acc = 0.f;
    #pragma unroll
    for (int k = 0; k < CIN; ++k) acc += h[(size_t)n*CIN + k] * u[k*8 + hd];
    a[idx] = acc;
}

// ---------------- sc = softmax(c) (self-loop attention, node-uniform) -----
__global__ void sc_kernel(const float* __restrict__ c, float* __restrict__ sc) {
    float m = c[0];
    for (int h = 1; h < 8; ++h) m = fmaxf(m, c[h]);
    float s = 0.f; float e[8];
    for (int h = 0; h < 8; ++h) { e[h] = expf(c[h] - m); s += e[h]; }
    for (int h = 0; h < 8; ++h) sc[h] = e[h] / s;
}

// ---------------- proj chunk: yc[n][h][oc] = h[n] @ W[:, h*O + o0 + oc] ---
// One 16-node tile per block; blockDim.x == 8*OC (<=256). Weights for this
// thread's column live in registers (compile-time indices only); per node
// pair the accumulators are named scalars -> no scratch, ~90 VGPR.
template<int CIN>
__global__ __launch_bounds__(256) void proj_kernel(
        const float* __restrict__ h, const float* __restrict__ W,
        float* __restrict__ yc, int HC, int O, int o0, int oc_sh) {
    __shared__ float hs[TN][CIN];
    const int tid = threadIdx.x;
    const int cols = blockDim.x;            // 8*OC
    const int hd = tid >> oc_sh;
    const int oc = tid & ((1 << oc_sh) - 1);
    const int wcol = hd * O + o0 + oc;
    float wreg[CIN];
    #pragma unroll
    for (int k = 0; k < CIN; ++k) wreg[k] = W[(size_t)k*HC + wcol];
    const int n0 = blockIdx.x * TN;
    for (int i = tid; i < TN*CIN; i += cols) {
        int t = i / CIN, k = i - t*CIN;     // CIN pow2 -> shift/and
        hs[t][k] = h[(size_t)(n0+t)*CIN + k];
    }
    __syncthreads();
    #pragma unroll 1
    for (int t = 0; t < TN; t += 2) {
        float a0=0.f,a1=0.f,a2=0.f,a3=0.f, b0=0.f,b1=0.f,b2=0.f,b3=0.f;
        #pragma unroll
        for (int k = 0; k < CIN; k += 4) {
            float4 ha = *(const float4*)&hs[t][k];
            float4 hb = *(const float4*)&hs[t+1][k];
            a0 += ha.x*wreg[k+0]; a1 += ha.y*wreg[k+1];
            a2 += ha.z*wreg[k+2]; a3 += ha.w*wreg[k+3];
            b0 += hb.x*wreg[k+0]; b1 += hb.y*wreg[k+1];
            b2 += hb.z*wreg[k+2]; b3 += hb.w*wreg[k+3];
        }
        yc[(size_t)(n0+t)*cols + tid]   = (a0+a1)+(a2+a3);
        yc[(size_t)(n0+t+1)*cols + tid] = (b0+b1)+(b2+b3);
    }
}

// ---------------- q: per-edge head softmax of a[s]-a[d]+c ----------------
__global__ void q_kernel(const int* __restrict__ src,
                         const int* __restrict__ dst,
                         const float* __restrict__ a,
                         const float* __restrict__ c,
                         float* __restrict__ q) {
    int e = blockIdx.x * 256 + threadIdx.x;
    if (e >= NE) return;
    int s = src[e], d = dst[e];
    const float4* as = (const float4*)(a + (size_t)s*8);
    const float4* ad = (const float4*)(a + (size_t)d*8);
    float4 s0 = as[0], s1 = as[1], d0 = ad[0], d1 = ad[1];
    float lg[8] = { s0.x-d0.x+c[0], s0.y-d0.y+c[1], s0.z-d0.z+c[2], s0.w-d0.w+c[3],
                    s1.x-d1.x+c[4], s1.y-d1.y+c[5], s1.z-d1.z+c[6], s1.w-d1.w+c[7] };
    float m = lg[0];
    #pragma unroll
    for (int h = 1; h < 8; ++h) m = fmaxf(m, lg[h]);
    float sum = 0.f;
    #pragma unroll
    for (int h = 0; h < 8; ++h) { lg[h] = expf(lg[h]-m); sum += lg[h]; }
    float inv = 1.f / sum;
    float4* qp = (float4*)(q + (size_t)e*8);
    qp[0] = make_float4(lg[0]*inv, lg[1]*inv, lg[2]*inv, lg[3]*inv);
    qp[1] = make_float4(lg[4]*inv, lg[5]*inv, lg[6]*inv, lg[7]*inv);
}

// ---------------- self-loop add: agg[n, o0+oc] += sum_h sc[h]*yc[n][h][oc] -
__global__ void self_kernel(const float* __restrict__ yc,
                            const float* __restrict__ sc,
                            float* __restrict__ agg,
                            int O, int o0, int oc_sh) {
    int OC = 1 << oc_sh;
    int idx = blockIdx.x * 256 + threadIdx.x;
    if (idx >= NN * OC) return;
    int n = idx >> oc_sh, oc = idx & (OC - 1);
    float v = 0.f;
    #pragma unroll
    for (int h = 0; h < 8; ++h) v += sc[h] * yc[(size_t)n*(8*OC) + h*OC + oc];
    agg[(size_t)n*O + o0 + oc] += v;
}

// ---------------- msg chunk: agg[d, o0..o0+OC) += sum_h q[e,h]*yc[s][h][..]
__global__ void msg_kernel(const int* __restrict__ src,
                           const int* __restrict__ dst,
                           const float* __restrict__ q,
                           const float* __restrict__ yc,
                           float* __restrict__ agg,
                           int O, int o0, int tpe_sh) {
    int gid = blockIdx.x * 256 + threadIdx.x;
    int e = gid >> tpe_sh;
    if (e >= NE) return;
    int lane = gid & ((1 << tpe_sh) - 1);
    int oc4 = 1 << tpe_sh;              // OC/4
    int s = src[e], d = dst[e];
    const float4* yr = (const float4*)(yc + (size_t)s * (oc4 << 5));  // 8*OC floats
    const float4* qp = (const float4*)(q + (size_t)e * 8);
    float4 q0 = qp[0], q1 = qp[1];
    float qh[8] = {q0.x, q0.y, q0.z, q0.w, q1.x, q1.y, q1.z, q1.w};
    float4 acc = make_float4(0.f, 0.f, 0.f, 0.f);
    #pragma unroll
    for (int h = 0; h < 8; ++h) {
        float4 v = yr[h*oc4 + lane];
        acc.x += qh[h]*v.x; acc.y += qh[h]*v.y;
        acc.z += qh[h]*v.z; acc.w += qh[h]*v.w;
    }
    float* ag = agg + (size_t)d*O + o0 + (lane << 2);
    atomicAdd(ag+0, acc.x); atomicAdd(ag+1, acc.y);
    atomicAdd(ag+2, acc.z); atomicAdd(ag+3, acc.w);
}

// ---------------- finalize: out = relu(agg/cnt + b) ----------------
__global__ void finalize_kernel(const float* __restrict__ agg,
                                const float* __restrict__ cnt,
                                const float* __restrict__ b,
                                float* __restrict__ out, int o_sh) {
    int O = 1 << o_sh;
    int idx = blockIdx.x * 256 + threadIdx.x;
    if (idx >= NN * O) return;
    int n = idx >> o_sh, o = idx & (O - 1);
    out[idx] = fmaxf(agg[idx] / cnt[n] + b[o], 0.f);
}

// ---------------- degree ----------------
__global__ void cnt_init_kernel(float* cnt) {
    int n = blockIdx.x * 256 + threadIdx.x;
    if (n < NN) cnt[n] = 1.0f;   // self loop
}
__global__ void indeg_kernel(const int* __restrict__ dst, float* cnt) {
    int e = blockIdx.x * 256 + threadIdx.x;
    if (e < NE) atomicAdd(&cnt[dst[e]], 1.0f);
}

// ---------------- fused lin2(relu) + lin3 + sigmoid ----------------
__global__ __launch_bounds__(256) void lin23_kernel(
        const float* __restrict__ h, const float* __restrict__ w2,
        const float* __restrict__ b2, const float* __restrict__ w3,
        const float* __restrict__ b3, float* __restrict__ p) {
    __shared__ float hs[16][128];
    __shared__ float red[4*16];
    const int tid = threadIdx.x;
    const int n0 = blockIdx.x * 16;
    for (int i = tid; i < 16*128; i += 256) {
        int t = i >> 7, k = i & 127;
        hs[t][k] = (n0 + t < NN) ? h[(size_t)(n0+t)*128 + k] : 0.f;
    }
    __syncthreads();
    float part[16];
    #pragma unroll
    for (int t = 0; t < 16; ++t) part[t] = 0.f;
    for (int cc = 0; cc < 4; ++cc) {
        int col = tid + cc*256;
        float acc[16];
        float bb = b2[col];
        #pragma unroll
        for (int t = 0; t < 16; ++t) acc[t] = bb;
        for (int k = 0; k < 128; k += 4) {
            float wa = w2[(size_t)(k+0)*1024 + col];
            float wb = w2[(size_t)(k+1)*1024 + col];
            float wc = w2[(size_t)(k+2)*1024 + col];
            float wd = w2[(size_t)(k+3)*1024 + col];
            #pragma unroll
            for (int t = 0; t < 16; ++t) {
                float4 hv = *(const float4*)&hs[t][k];
                acc[t] += hv.x*wa + hv.y*wb + hv.z*wc + hv.w*wd;
            }
        }
        float w3c = w3[col];
        #pragma unroll
        for (int t = 0; t < 16; ++t) part[t] += fmaxf(acc[t], 0.f) * w3c;
    }
    #pragma unroll
    for (int t = 0; t < 16; ++t) {
        float v = part[t];
        #pragma unroll
        for (int off = 32; off; off >>= 1) v += __shfl_down(v, off, 64);
        if ((tid & 63) == 0) red[(tid >> 6)*16 + t] = v;
    }
    __syncthreads();
    if (tid < 16) {
        int n = n0 + tid;
        if (n < NN) {
            float z = red[tid] + red[16+tid] + red[32+tid] + red[48+tid] + b3[0];
            p[n] = 1.f / (1.f + expf(-z));
        }
    }
}

// ---------------- loss ----------------
__global__ void loss_pass_kernel(const float* __restrict__ labels,
                                 const float* __restrict__ p,
                                 float* __restrict__ scal) {
    __shared__ float sh0[256], sh1[256], sh2[256];
    int tid = threadIdx.x;
    float pos = 0.f, sp = 0.f, sn = 0.f;
    for (int n = blockIdx.x*256 + tid; n < NN; n += gridDim.x*256) {
        float yv = labels[n], pv = p[n];
        if (yv == 1.0f) { pos += 1.f; sp -= fmaxf(logf(pv), -100.f); }
        else            { sn -= fmaxf(logf(1.f - pv), -100.f); }
    }
    sh0[tid] = pos; sh1[tid] = sp; sh2[tid] = sn;
    __syncthreads();
    for (int off = 128; off; off >>= 1) {
        if (tid < off) {
            sh0[tid] += sh0[tid+off];
            sh1[tid] += sh1[tid+off];
            sh2[tid] += sh2[tid+off];
        }
        __syncthreads();
    }
    if (tid == 0) {
        atomicAdd(&scal[0], sh0[0]);
        atomicAdd(&scal[1], sh1[0]);
        atomicAdd(&scal[2], sh2[0]);
    }
}

__global__ void loss_final_kernel(const float* __restrict__ scal,
                                  float* __restrict__ out) {
    float pos = scal[0];
    out[0] = scal[1] / (2.f*pos) + scal[2] / (2.f*((float)NN - pos));
}

// ---------------- launch ----------------
extern "C" void kernel_launch(void* const* d_in, const int* in_sizes, int n_in,
                              void* d_out, int out_size, void* d_ws, size_t ws_size,
                              hipStream_t stream) {
    (void)in_sizes; (void)n_in; (void)out_size;
    const float* x   = (const float*)d_in[0];
    const int*   ei  = (const int*)d_in[1];      // int32 per harness contract
    const float* labels = (const float*)d_in[2];
    const float* l1w = (const float*)d_in[3];
    const float* l1b = (const float*)d_in[4];
    const float* cw[3] = {(const float*)d_in[5], (const float*)d_in[9],  (const float*)d_in[13]};
    const float* cu[3] = {(const float*)d_in[6], (const float*)d_in[10], (const float*)d_in[14]};
    const float* cc[3] = {(const float*)d_in[7], (const float*)d_in[11], (const float*)d_in[15]};
    const float* cb[3] = {(const float*)d_in[8], (const float*)d_in[12], (const float*)d_in[16]};
    const float* l2w = (const float*)d_in[17];
    const float* l2b = (const float*)d_in[18];
    const float* l3w = (const float*)d_in[19];
    const float* l3b = (const float*)d_in[20];
    const int* srcp = ei;
    const int* dstp = ei + NE;
    float* out = (float*)d_out;

    // ---- workspace layout (16-float aligned blocks) ----
    float* ws = (float*)d_ws;
    size_t off = 0;
    auto alloc = [&](size_t n) { float* p = ws + off; off += (n + 15) & ~(size_t)15; return p; };
    float* h1   = alloc((size_t)NN*16);
    float* h2   = alloc((size_t)NN*32);
    float* h3   = alloc((size_t)NN*64);
    float* h4   = alloc((size_t)NN*128);
    float* a    = alloc((size_t)NN*8);
    float* q    = alloc((size_t)NE*8);
    float* agg  = alloc((size_t)NN*128);
    float* cnt  = alloc((size_t)NN);
    float* scal = alloc(16);
    float* sc   = alloc(16);
    // adaptive chunk width for the projected-feature buffer yc (N x 8 x OC)
    int oc_sh = 3;                                               // OC = 8
    if ((off + (size_t)NN*8*32) * 4 <= ws_size) oc_sh = 5;       // OC = 32
    else if ((off + (size_t)NN*8*16) * 4 <= ws_size) oc_sh = 4;  // OC = 16
    const int OC = 1 << oc_sh;
    float* yc = ws + off;

    // ---- degree (layer-independent) + scalar zero ----
    cnt_init_kernel<<<(NN+255)/256, 256, 0, stream>>>(cnt);
    indeg_kernel<<<(NE+255)/256, 256, 0, stream>>>(dstp, cnt);
    hipMemsetAsync(scal, 0, 16*sizeof(float), stream);

    // ---- lin1 ----
    lin1_kernel<<<(NN*16+255)/256, 256, 0, stream>>>(x, l1w, l1b, h1);

    // ---- three FeaStConv layers ----
    const float* hin_arr[3]  = {h1, h2, h3};
    float*       hout_arr[3] = {h2, h3, h4};
    const int    cin_arr[3]  = {16, 32, 64};
    const int    osh_arr[3]  = {5, 6, 7};     // O = 32, 64, 128

    for (int L = 0; L < 3; ++L) {
        const float* hin = hin_arr[L];
        float* hout = hout_arr[L];
        const int O = 1 << osh_arr[L];
        const int HC = 8 * O;

        if (cin_arr[L] == 16)      a_kernel<16><<<(NN*8+255)/256, 256, 0, stream>>>(hin, cu[L], a);
        else if (cin_arr[L] == 32) a_kernel<32><<<(NN*8+255)/256, 256, 0, stream>>>(hin, cu[L], a);
        else                       a_kernel<64><<<(NN*8+255)/256, 256, 0, stream>>>(hin, cu[L], a);
        sc_kernel<<<1, 1, 0, stream>>>(cc[L], sc);
        q_kernel<<<(NE+255)/256, 256, 0, stream>>>(srcp, dstp, a, cc[L], q);
        hipMemsetAsync(agg, 0, (size_t)NN*O*sizeof(float), stream);

        const int nchunk = O / OC;
        const int tpe_sh = oc_sh - 2;    // OC/4 threads per edge
        const int cols = 8 * OC;         // proj block size
        for (int ch = 0; ch < nchunk; ++ch) {
            const int o0 = ch * OC;
            if (cin_arr[L] == 16)
                proj_kernel<16><<<NN/TN, cols, 0, stream>>>(hin, cw[L], yc, HC, O, o0, oc_sh);
            else if (cin_arr[L] == 32)
                proj_kernel<32><<<NN/TN, cols, 0, stream>>>(hin, cw[L], yc, HC, O, o0, oc_sh);
            else
                proj_kernel<64><<<NN/TN, cols, 0, stream>>>(hin, cw[L], yc, HC, O, o0, oc_sh);
            self_kernel<<<((size_t)NN*OC+255)/256, 256, 0, stream>>>(yc, sc, agg, O, o0, oc_sh);
            msg_kernel<<<(((size_t)NE<<tpe_sh)+255)/256, 256, 0, stream>>>(srcp, dstp, q, yc, agg, O, o0, tpe_sh);
        }
        finalize_kernel<<<((size_t)NN*O+255)/256, 256, 0, stream>>>(agg, cnt, cb[L], hout, osh_arr[L]);
    }

    // ---- fused lin2 + relu + lin3 + sigmoid -> p ----
    lin23_kernel<<<(NN+15)/16, 256, 0, stream>>>(h4, l2w, l2b, l3w, l3b, out + 1);

    // ---- class-balanced BCE loss ----
    loss_pass_kernel<<<256, 256, 0, stream>>>(labels, out + 1, scal);
    loss_final_kernel<<<1, 1, 0, stream>>>(scal, out);
}

// Round 5
// 372.782 us; speedup vs baseline: 14.7563x; 4.3223x over previous
//
#include <hip/hip_runtime.h>
#include <math.h>

#define NN 50000
#define NE 300000

typedef short s8v __attribute__((ext_vector_type(8)));
typedef float f4v __attribute__((ext_vector_type(4)));

__device__ inline unsigned short f2bf(float f) {
    union { float f; unsigned int u; } v; v.f = f;
    unsigned int r = v.u + 0x7FFFu + ((v.u >> 16) & 1u);
    return (unsigned short)(r >> 16);
}

// ---------------- lin1: hA = relu(x @ W(3,16) + b) ----------------
__global__ void lin1_kernel(const float* __restrict__ x,
                            const float* __restrict__ w,
                            const float* __restrict__ b,
                            float* __restrict__ out) {
    int idx = blockIdx.x * 256 + threadIdx.x;
    if (idx >= NN * 16) return;
    int n = idx >> 4, o = idx & 15;
    float v = x[n*3+0]*w[o] + x[n*3+1]*w[16+o] + x[n*3+2]*w[32+o] + b[o];
    out[idx] = fmaxf(v, 0.f);
}

// ---------------- a = h @ u  (N x 8) ----------------
template<int CIN>
__global__ void a_kernel(const float* __restrict__ h,
                         const float* __restrict__ u,
                         float* __restrict__ a) {
    int idx = blockIdx.x * 256 + threadIdx.x;
    if (idx >= NN * 8) return;
    int n = idx >> 3, hd = idx & 7;
    float acc = 0.f;
    #pragma unroll
    for (int k = 0; k < CIN; ++k) acc += h[(size_t)n*CIN + k] * u[k*8 + hd];
    a[idx] = acc;
}

// ---------------- sc = softmax(c) ----------------
__global__ void sc_kernel(const float* __restrict__ c, float* __restrict__ sc) {
    float m = c[0];
    for (int h = 1; h < 8; ++h) m = fmaxf(m, c[h]);
    float s = 0.f; float e[8];
    for (int h = 0; h < 8; ++h) { e[h] = expf(c[h] - m); s += e[h]; }
    for (int h = 0; h < 8; ++h) sc[h] = e[h] / s;
}

// ---------------- CSR build ----------------
__global__ void hist_kernel(const int* __restrict__ dst, int* __restrict__ cnt) {
    int e = blockIdx.x * 256 + threadIdx.x;
    if (e < NE) atomicAdd(&cnt[dst[e]], 1);
}

__global__ void scan1_kernel(const int* __restrict__ cnt, int* __restrict__ rp,
                             int* __restrict__ bpart) {
    __shared__ int sh[256];
    int tid = threadIdx.x;
    int gid = blockIdx.x * 256 + tid;
    int v = (gid < NN) ? cnt[gid] : 0;
    sh[tid] = v;
    __syncthreads();
    for (int off = 1; off < 256; off <<= 1) {
        int t = (tid >= off) ? sh[tid - off] : 0;
        __syncthreads();
        sh[tid] += t;
        __syncthreads();
    }
    if (gid < NN) rp[gid] = sh[tid] - v;            // exclusive
    if (tid == 255) bpart[blockIdx.x] = sh[tid];    // block total
}

__global__ void scan2_kernel(int* __restrict__ bpart, int nblk) {
    __shared__ int sh[256];
    int tid = threadIdx.x;
    int v = (tid < nblk) ? bpart[tid] : 0;
    sh[tid] = v;
    __syncthreads();
    for (int off = 1; off < 256; off <<= 1) {
        int t = (tid >= off) ? sh[tid - off] : 0;
        __syncthreads();
        sh[tid] += t;
        __syncthreads();
    }
    bpart[tid] = sh[tid] - v;                        // exclusive
}

__global__ void scan3_kernel(int* __restrict__ rp, const int* __restrict__ bpart) {
    int gid = blockIdx.x * 256 + threadIdx.x;
    if (gid < NN) rp[gid] += bpart[blockIdx.x];
    if (gid == 0) rp[NN] = NE;
}

__global__ void scatter_kernel(const int* __restrict__ src, const int* __restrict__ dst,
                               const int* __restrict__ rp, int* __restrict__ fill,
                               int* __restrict__ ssrc) {
    int e = blockIdx.x * 256 + threadIdx.x;
    if (e >= NE) return;
    int d = dst[e];
    int pos = rp[d] + atomicAdd(&fill[d], 1);
    ssrc[pos] = src[e];
}

// ---------------- agg: g[d,h,k] = sc[h]*x[d,k] + sum_edges q[h]*x[s,k] ----
// one wave per dst; softmax fused (computed redundantly per lane)
template<int CIN>
__global__ __launch_bounds__(256) void agg_kernel(
        const float* __restrict__ hin, const float* __restrict__ a,
        const float* __restrict__ cbias, const float* __restrict__ sc,
        const int* __restrict__ rowptr, const int* __restrict__ ssrc,
        unsigned short* __restrict__ g) {
    constexpr int HPER = CIN / 8;                 // 2,4,8
    constexpr int LG = (CIN == 16) ? 4 : (CIN == 32) ? 5 : 6;
    const int lane = threadIdx.x & 63;
    const int d = blockIdx.x * 4 + (threadIdx.x >> 6);
    const int k = lane & (CIN - 1);
    const int hg = lane >> LG;
    float cc[8], ad[8];
    #pragma unroll
    for (int h = 0; h < 8; ++h) { cc[h] = cbias[h]; ad[h] = a[(size_t)d*8 + h]; }
    float xd = hin[(size_t)d*CIN + k];
    float acc[HPER];
    #pragma unroll
    for (int i = 0; i < HPER; ++i) acc[i] = sc[hg*HPER + i] * xd;
    int j0 = rowptr[d], j1 = rowptr[d+1];
    for (int j = j0; j < j1; ++j) {
        int s = ssrc[j];
        float xv = hin[(size_t)s*CIN + k];
        float lg[8];
        #pragma unroll
        for (int h = 0; h < 8; ++h) lg[h] = a[(size_t)s*8 + h] - ad[h] + cc[h];
        float m = lg[0];
        #pragma unroll
        for (int h = 1; h < 8; ++h) m = fmaxf(m, lg[h]);
        float sum = 0.f;
        #pragma unroll
        for (int h = 0; h < 8; ++h) { lg[h] = __expf(lg[h] - m); sum += lg[h]; }
        float inv = 1.f / sum;
        #pragma unroll
        for (int i = 0; i < HPER; ++i) acc[i] += lg[hg*HPER + i] * inv * xv;
    }
    #pragma unroll
    for (int i = 0; i < HPER; ++i)
        g[(size_t)d*(8*CIN) + (hg*HPER + i)*CIN + k] = f2bf(acc[i]);
}

// ---------------- pack feast W into B-frag order ----------------
// B[kk][c], kk=h*CIN+k_in, c in O; frag: lane l elem i = B[s*32+(l>>4)*8+i][ct*16+(l&15)]
template<int CIN, int O>
__global__ void packw_feast(const float* __restrict__ W, unsigned short* __restrict__ wp) {
    constexpr int NS = (8*CIN) / 32;
    constexpr int TOT = (O/16) * NS * 64;
    int t = blockIdx.x * 256 + threadIdx.x;
    if (t >= TOT) return;
    int l = t & 63;
    int s = (t >> 6) % NS;
    int ct = t / (64 * NS);
    int c = ct*16 + (l & 15);
    int kk0 = s*32 + (l >> 4) * 8;
    union { unsigned short u[8]; s8v v; } o;
    #pragma unroll
    for (int i = 0; i < 8; ++i) {
        int kk = kk0 + i;
        int h = kk / CIN, k = kk & (CIN - 1);
        o.u[i] = f2bf(W[(size_t)k*(8*O) + h*O + c]);
    }
    *(s8v*)(wp + (size_t)t*8) = o.v;
}

// ---------------- pack lin2 W (128 x 1024) ----------------
__global__ void packw_lin(const float* __restrict__ W, unsigned short* __restrict__ wp) {
    int t = blockIdx.x * 256 + threadIdx.x;      // (ctg*4 + s)*64 + l, ctg<64
    if (t >= 64*4*64) return;
    int l = t & 63;
    int s = (t >> 6) & 3;
    int ctg = t >> 8;
    int c = ctg*16 + (l & 15);
    int k0 = s*32 + (l >> 4) * 8;
    union { unsigned short u[8]; s8v v; } o;
    #pragma unroll
    for (int i = 0; i < 8; ++i) o.u[i] = f2bf(W[(size_t)(k0+i)*1024 + c]);
    *(s8v*)(wp + (size_t)t*8) = o.v;
}

// ---------------- feast GEMM: hout = relu(g @ Wp / cnt + b) ----------------
template<int K, int O>
__global__ __launch_bounds__(256) void gemm_feast(
        const unsigned short* __restrict__ g, const unsigned short* __restrict__ wp,
        const int* __restrict__ rowptr, const float* __restrict__ b,
        float* __restrict__ hout) {
    constexpr int NS = K / 32;
    const int l = threadIdx.x & 63;
    const int w = threadIdx.x >> 6;
    const int base = blockIdx.x * 64 + w * 16;
    int arow = base + (l & 15); if (arow >= NN) arow = NN - 1;
    const int koff = (l >> 4) * 8;
    s8v af[NS];
    #pragma unroll
    for (int s = 0; s < NS; ++s)
        af[s] = *(const s8v*)(g + (size_t)arow*K + s*32 + koff);
    float invc[4];
    #pragma unroll
    for (int r = 0; r < 4; ++r) {
        int n = base + (l >> 4)*4 + r; if (n >= NN) n = NN - 1;
        invc[r] = 1.f / (float)(rowptr[n+1] - rowptr[n] + 1);
    }
    #pragma unroll 1
    for (int ct = 0; ct < O/16; ++ct) {
        f4v acc = {0.f, 0.f, 0.f, 0.f};
        #pragma unroll
        for (int s = 0; s < NS; ++s) {
            s8v bf = *(const s8v*)(wp + ((size_t)(ct*NS + s)*64 + l)*8);
            acc = __builtin_amdgcn_mfma_f32_16x16x32_bf16(af[s], bf, acc, 0, 0, 0);
        }
        int col = ct*16 + (l & 15);
        float bb = b[col];
        #pragma unroll
        for (int r = 0; r < 4; ++r) {
            int n = base + (l >> 4)*4 + r;
            if (n < NN) hout[(size_t)n*O + col] = fmaxf(acc[r]*invc[r] + bb, 0.f);
        }
    }
}

// ---------------- fused lin2(relu)+lin3+sigmoid via MFMA ----------------
__global__ __launch_bounds__(256) void lin23_mfma(
        const unsigned short* __restrict__ h4b, const unsigned short* __restrict__ w2p,
        const float* __restrict__ b2, const float* __restrict__ w3,
        const float* __restrict__ b3, float* __restrict__ p) {
    __shared__ float zred[64];
    const int l = threadIdx.x & 63;
    const int w = threadIdx.x >> 6;
    const int base = blockIdx.x * 16;
    const int arow = base + (l & 15);
    const int koff = (l >> 4) * 8;
    s8v af[4];
    #pragma unroll
    for (int s = 0; s < 4; ++s)
        af[s] = *(const s8v*)(h4b + (size_t)arow*128 + s*32 + koff);
    float zp0 = 0.f, zp1 = 0.f, zp2 = 0.f, zp3 = 0.f;
    #pragma unroll 1
    for (int ct = 0; ct < 16; ++ct) {
        f4v acc = {0.f, 0.f, 0.f, 0.f};
        #pragma unroll
        for (int s = 0; s < 4; ++s) {
            s8v bf = *(const s8v*)(w2p + ((size_t)((w*16 + ct)*4 + s)*64 + l)*8);
            acc = __builtin_amdgcn_mfma_f32_16x16x32_bf16(af[s], bf, acc, 0, 0, 0);
        }
        int col = w*256 + ct*16 + (l & 15);
        float w3c = w3[col], bb = b2[col];
        zp0 += fmaxf(acc[0] + bb, 0.f) * w3c;
        zp1 += fmaxf(acc[1] + bb, 0.f) * w3c;
        zp2 += fmaxf(acc[2] + bb, 0.f) * w3c;
        zp3 += fmaxf(acc[3] + bb, 0.f) * w3c;
    }
    #pragma unroll
    for (int off = 1; off < 16; off <<= 1) {
        zp0 += __shfl_xor(zp0, off, 64);
        zp1 += __shfl_xor(zp1, off, 64);
        zp2 += __shfl_xor(zp2, off, 64);
        zp3 += __shfl_xor(zp3, off, 64);
    }
    if ((l & 15) == 0) {
        int t = (l >> 4) * 4;
        zred[w*16 + t+0] = zp0; zred[w*16 + t+1] = zp1;
        zred[w*16 + t+2] = zp2; zred[w*16 + t+3] = zp3;
    }
    __syncthreads();
    if (threadIdx.x < 16) {
        float z = zred[threadIdx.x] + zred[16 + threadIdx.x]
                + zred[32 + threadIdx.x] + zred[48 + threadIdx.x] + b3[0];
        p[base + threadIdx.x] = 1.f / (1.f + expf(-z));
    }
}

// ---------------- f32 -> bf16 convert (N*128) ----------------
__global__ void cvt_kernel(const float* __restrict__ in, unsigned short* __restrict__ out) {
    int i = blockIdx.x * 256 + threadIdx.x;
    if (i >= NN * 32) return;      // NN*128/4
    float4 v = ((const float4*)in)[i];
    ushort4 o;
    o.x = f2bf(v.x); o.y = f2bf(v.y); o.z = f2bf(v.z); o.w = f2bf(v.w);
    ((ushort4*)out)[i] = o;
}

// ---------------- loss ----------------
__global__ void loss_pass_kernel(const float* __restrict__ labels,
                                 const float* __restrict__ p,
                                 float* __restrict__ scal) {
    __shared__ float sh0[256], sh1[256], sh2[256];
    int tid = threadIdx.x;
    float pos = 0.f, sp = 0.f, sn = 0.f;
    for (int n = blockIdx.x*256 + tid; n < NN; n += gridDim.x*256) {
        float yv = labels[n], pv = p[n];
        if (yv == 1.0f) { pos += 1.f; sp -= fmaxf(logf(pv), -100.f); }
        else            { sn -= fmaxf(logf(1.f - pv), -100.f); }
    }
    sh0[tid] = pos; sh1[tid] = sp; sh2[tid] = sn;
    __syncthreads();
    for (int off = 128; off; off >>= 1) {
        if (tid < off) {
            sh0[tid] += sh0[tid+off];
            sh1[tid] += sh1[tid+off];
            sh2[tid] += sh2[tid+off];
        }
        __syncthreads();
    }
    if (tid == 0) {
        atomicAdd(&scal[0], sh0[0]);
        atomicAdd(&scal[1], sh1[0]);
        atomicAdd(&scal[2], sh2[0]);
    }
}

__global__ void loss_final_kernel(const float* __restrict__ scal,
                                  float* __restrict__ out) {
    float pos = scal[0];
    out[0] = scal[1] / (2.f*pos) + scal[2] / (2.f*((float)NN - pos));
}

// ---------------- launch ----------------
extern "C" void kernel_launch(void* const* d_in, const int* in_sizes, int n_in,
                              void* d_out, int out_size, void* d_ws, size_t ws_size,
                              hipStream_t stream) {
    (void)in_sizes; (void)n_in; (void)out_size; (void)ws_size;
    const float* x   = (const float*)d_in[0];
    const int*   ei  = (const int*)d_in[1];
    const float* labels = (const float*)d_in[2];
    const float* l1w = (const float*)d_in[3];
    const float* l1b = (const float*)d_in[4];
    const float* cw[3] = {(const float*)d_in[5], (const float*)d_in[9],  (const float*)d_in[13]};
    const float* cu[3] = {(const float*)d_in[6], (const float*)d_in[10], (const float*)d_in[14]};
    const float* cc[3] = {(const float*)d_in[7], (const float*)d_in[11], (const float*)d_in[15]};
    const float* cb[3] = {(const float*)d_in[8], (const float*)d_in[12], (const float*)d_in[16]};
    const float* l2w = (const float*)d_in[17];
    const float* l2b = (const float*)d_in[18];
    const float* l3w = (const float*)d_in[19];
    const float* l3b = (const float*)d_in[20];
    const int* srcp = ei;
    const int* dstp = ei + NE;
    float* out = (float*)d_out;

    // ---- workspace (float units, 64B aligned) : total ~93 MB ----
    float* ws = (float*)d_ws;
    size_t off = 0;
    auto alloc = [&](size_t n) { float* p = ws + off; off += (n + 15) & ~(size_t)15; return p; };
    float* hA = alloc((size_t)NN*64);                 // holds h1(N,16) and h3(N,64)
    float* hB = alloc((size_t)NN*128);                // holds h2(N,32) and h4(N,128)
    float* a  = alloc((size_t)NN*8);
    unsigned short* g  = (unsigned short*)alloc((size_t)NN*256);  // N x 512 bf16 max
    unsigned short* w2p = (unsigned short*)alloc(65536);
    unsigned short* wfp = (unsigned short*)alloc(32768);
    float* sc   = alloc(16);
    float* scal = alloc(16);
    int* rowptr = (int*)alloc(50016);
    int* fill   = (int*)alloc(50000);
    int* ssrc   = (int*)alloc(NE);
    int* bpart  = (int*)alloc(256);
    unsigned short* h4b = g;                          // reuse g after conv3 GEMM

    const int SCAN_BLKS = (NN + 255) / 256;           // 196

    // ---- CSR build ----
    hipMemsetAsync(fill, 0, NN*sizeof(int), stream);
    hist_kernel<<<(NE+255)/256, 256, 0, stream>>>(dstp, fill);
    scan1_kernel<<<SCAN_BLKS, 256, 0, stream>>>(fill, rowptr, bpart);
    scan2_kernel<<<1, 256, 0, stream>>>(bpart, SCAN_BLKS);
    scan3_kernel<<<SCAN_BLKS, 256, 0, stream>>>(rowptr, bpart);
    hipMemsetAsync(fill, 0, NN*sizeof(int), stream);
    scatter_kernel<<<(NE+255)/256, 256, 0, stream>>>(srcp, dstp, rowptr, fill, ssrc);

    // ---- lin1 ----
    lin1_kernel<<<(NN*16+255)/256, 256, 0, stream>>>(x, l1w, l1b, hA);

    // ---- conv1: cin=16 -> O=32 (hA -> hB) ----
    sc_kernel<<<1, 1, 0, stream>>>(cc[0], sc);
    a_kernel<16><<<(NN*8+255)/256, 256, 0, stream>>>(hA, cu[0], a);
    agg_kernel<16><<<NN/4, 256, 0, stream>>>(hA, a, cc[0], sc, rowptr, ssrc, g);
    packw_feast<16,32><<<2, 256, 0, stream>>>(cw[0], wfp);
    gemm_feast<128,32><<<(NN+63)/64, 256, 0, stream>>>(g, wfp, rowptr, cb[0], hB);

    // ---- conv2: cin=32 -> O=64 (hB -> hA) ----
    sc_kernel<<<1, 1, 0, stream>>>(cc[1], sc);
    a_kernel<32><<<(NN*8+255)/256, 256, 0, stream>>>(hB, cu[1], a);
    agg_kernel<32><<<NN/4, 256, 0, stream>>>(hB, a, cc[1], sc, rowptr, ssrc, g);
    packw_feast<32,64><<<8, 256, 0, stream>>>(cw[1], wfp);
    gemm_feast<256,64><<<(NN+63)/64, 256, 0, stream>>>(g, wfp, rowptr, cb[1], hA);

    // ---- conv3: cin=64 -> O=128 (hA -> hB) ----
    sc_kernel<<<1, 1, 0, stream>>>(cc[2], sc);
    a_kernel<64><<<(NN*8+255)/256, 256, 0, stream>>>(hA, cu[2], a);
    agg_kernel<64><<<NN/4, 256, 0, stream>>>(hA, a, cc[2], sc, rowptr, ssrc, g);
    packw_feast<64,128><<<32, 256, 0, stream>>>(cw[2], wfp);
    gemm_feast<512,128><<<(NN+63)/64, 256, 0, stream>>>(g, wfp, rowptr, cb[2], hB);

    // ---- lin2+lin3+sigmoid ----
    cvt_kernel<<<(NN*32+255)/256, 256, 0, stream>>>(hB, h4b);
    packw_lin<<<64, 256, 0, stream>>>(l2w, w2p);
    lin23_mfma<<<NN/16, 256, 0, stream>>>(h4b, w2p, l2b, l3w, l3b, out + 1);

    // ---- loss ----
    hipMemsetAsync(scal, 0, 16*sizeof(float), stream);
    loss_pass_kernel<<<256, 256, 0, stream>>>(labels, out + 1, scal);
    loss_final_kernel<<<1, 1, 0, stream>>>(scal, out);
}

// Round 6
// 324.765 us; speedup vs baseline: 16.9380x; 1.1479x over previous
//
#include <hip/hip_runtime.h>
#include <math.h>

#define NN 50000
#define NE 300000

typedef short s8v __attribute__((ext_vector_type(8)));
typedef float f4v __attribute__((ext_vector_type(4)));

__device__ inline unsigned short f2bf(float f) {
    union { float f; unsigned int u; } v; v.f = f;
    unsigned int r = v.u + 0x7FFFu + ((v.u >> 16) & 1u);
    return (unsigned short)(r >> 16);
}

// ---------------- lin1: hA = relu(x @ W(3,16) + b) ----------------
__global__ void lin1_kernel(const float* __restrict__ x,
                            const float* __restrict__ w,
                            const float* __restrict__ b,
                            float* __restrict__ out) {
    int idx = blockIdx.x * 256 + threadIdx.x;
    if (idx >= NN * 16) return;
    int n = idx >> 4, o = idx & 15;
    float v = x[n*3+0]*w[o] + x[n*3+1]*w[16+o] + x[n*3+2]*w[32+o] + b[o];
    out[idx] = fmaxf(v, 0.f);
}

// ---------------- a = h @ u  (N x 8) ----------------
template<int CIN>
__global__ void a_kernel(const float* __restrict__ h,
                         const float* __restrict__ u,
                         float* __restrict__ a) {
    int idx = blockIdx.x * 256 + threadIdx.x;
    if (idx >= NN * 8) return;
    int n = idx >> 3, hd = idx & 7;
    float acc = 0.f;
    #pragma unroll
    for (int k = 0; k < CIN; ++k) acc += h[(size_t)n*CIN + k] * u[k*8 + hd];
    a[idx] = acc;
}

// ---------------- sc = softmax(c) ----------------
__global__ void sc_kernel(const float* __restrict__ c, float* __restrict__ sc) {
    float m = c[0];
    for (int h = 1; h < 8; ++h) m = fmaxf(m, c[h]);
    float s = 0.f; float e[8];
    for (int h = 0; h < 8; ++h) { e[h] = expf(c[h] - m); s += e[h]; }
    for (int h = 0; h < 8; ++h) sc[h] = e[h] / s;
}

// ---------------- CSR build ----------------
__global__ void hist_kernel(const int* __restrict__ dst, int* __restrict__ cnt) {
    int e = blockIdx.x * 256 + threadIdx.x;
    if (e < NE) atomicAdd(&cnt[dst[e]], 1);
}

__global__ void scan1_kernel(const int* __restrict__ cnt, int* __restrict__ rp,
                             int* __restrict__ bpart) {
    __shared__ int sh[256];
    int tid = threadIdx.x;
    int gid = blockIdx.x * 256 + tid;
    int v = (gid < NN) ? cnt[gid] : 0;
    sh[tid] = v;
    __syncthreads();
    for (int off = 1; off < 256; off <<= 1) {
        int t = (tid >= off) ? sh[tid - off] : 0;
        __syncthreads();
        sh[tid] += t;
        __syncthreads();
    }
    if (gid < NN) rp[gid] = sh[tid] - v;            // exclusive
    if (tid == 255) bpart[blockIdx.x] = sh[tid];    // block total
}

__global__ void scan2_kernel(int* __restrict__ bpart, int nblk) {
    __shared__ int sh[256];
    int tid = threadIdx.x;
    int v = (tid < nblk) ? bpart[tid] : 0;
    sh[tid] = v;
    __syncthreads();
    for (int off = 1; off < 256; off <<= 1) {
        int t = (tid >= off) ? sh[tid - off] : 0;
        __syncthreads();
        sh[tid] += t;
        __syncthreads();
    }
    bpart[tid] = sh[tid] - v;                        // exclusive
}

__global__ void scan3_kernel(int* __restrict__ rp, const int* __restrict__ bpart) {
    int gid = blockIdx.x * 256 + threadIdx.x;
    if (gid < NN) rp[gid] += bpart[blockIdx.x];
    if (gid == 0) rp[NN] = NE;
}

__global__ void scatter_kernel(const int* __restrict__ src, const int* __restrict__ dst,
                               const int* __restrict__ rp, int* __restrict__ fill,
                               int* __restrict__ ssrc, int* __restrict__ sdst) {
    int e = blockIdx.x * 256 + threadIdx.x;
    if (e >= NE) return;
    int d = dst[e];
    int pos = rp[d] + atomicAdd(&fill[d], 1);
    ssrc[pos] = src[e];
    sdst[pos] = d;
}

// ---------------- q over sorted edges: qs[j,h] = softmax_h(a[s]-a[d]+c) ----
__global__ void q_sorted_kernel(const int* __restrict__ ssrc,
                                const int* __restrict__ sdst,
                                const float* __restrict__ a,
                                const float* __restrict__ c,
                                float* __restrict__ qs) {
    int j = blockIdx.x * 256 + threadIdx.x;
    if (j >= NE) return;
    int s = ssrc[j], d = sdst[j];
    const float4* as = (const float4*)(a + (size_t)s*8);
    const float4* ad = (const float4*)(a + (size_t)d*8);
    float4 s0 = as[0], s1 = as[1], d0 = ad[0], d1 = ad[1];
    float lg[8] = { s0.x-d0.x+c[0], s0.y-d0.y+c[1], s0.z-d0.z+c[2], s0.w-d0.w+c[3],
                    s1.x-d1.x+c[4], s1.y-d1.y+c[5], s1.z-d1.z+c[6], s1.w-d1.w+c[7] };
    float m = lg[0];
    #pragma unroll
    for (int h = 1; h < 8; ++h) m = fmaxf(m, lg[h]);
    float sum = 0.f;
    #pragma unroll
    for (int h = 0; h < 8; ++h) { lg[h] = __expf(lg[h]-m); sum += lg[h]; }
    float inv = 1.f / sum;
    float4* qp = (float4*)(qs + (size_t)j*8);
    qp[0] = make_float4(lg[0]*inv, lg[1]*inv, lg[2]*inv, lg[3]*inv);
    qp[1] = make_float4(lg[4]*inv, lg[5]*inv, lg[6]*inv, lg[7]*inv);
}

// ---------------- agg: g[d,h,k] = sc[h]*x[d,k] + sum_edges qs[j,h]*x[s,k] --
// one wave per dst; q precomputed -> per edge just loads + HPER fmas
template<int CIN>
__global__ __launch_bounds__(256) void agg_kernel(
        const float* __restrict__ hin, const float* __restrict__ sc,
        const int* __restrict__ rowptr, const int* __restrict__ ssrc,
        const float* __restrict__ qs, unsigned short* __restrict__ g) {
    constexpr int HPER = CIN / 8;                 // 2,4,8
    constexpr int LG = (CIN == 16) ? 4 : (CIN == 32) ? 5 : 6;
    const int lane = threadIdx.x & 63;
    const int d = blockIdx.x * 4 + (threadIdx.x >> 6);
    const int k = lane & (CIN - 1);
    const int hg = lane >> LG;                    // head-group of this lane
    float xd = hin[(size_t)d*CIN + k];
    float acc[HPER];
    #pragma unroll
    for (int i = 0; i < HPER; ++i) acc[i] = sc[hg*HPER + i] * xd;
    int j0 = rowptr[d], j1 = rowptr[d+1];
    for (int j = j0; j < j1; ++j) {
        int s = ssrc[j];
        float xv = hin[(size_t)s*CIN + k];
        float qv[HPER];
        if constexpr (HPER == 2) {
            float2 t = *(const float2*)(qs + (size_t)j*8 + hg*2);
            qv[0] = t.x; qv[1] = t.y;
        } else if constexpr (HPER == 4) {
            float4 t = *(const float4*)(qs + (size_t)j*8 + hg*4);
            qv[0] = t.x; qv[1] = t.y; qv[2] = t.z; qv[3] = t.w;
        } else {
            float4 t0 = *(const float4*)(qs + (size_t)j*8);
            float4 t1 = *(const float4*)(qs + (size_t)j*8 + 4);
            qv[0] = t0.x; qv[1] = t0.y; qv[2] = t0.z; qv[3] = t0.w;
            qv[4] = t1.x; qv[5] = t1.y; qv[6] = t1.z; qv[7] = t1.w;
        }
        #pragma unroll
        for (int i = 0; i < HPER; ++i) acc[i] += qv[i] * xv;
    }
    #pragma unroll
    for (int i = 0; i < HPER; ++i)
        g[(size_t)d*(8*CIN) + (hg*HPER + i)*CIN + k] = f2bf(acc[i]);
}

// ---------------- pack feast W into B-frag order ----------------
template<int CIN, int O>
__global__ void packw_feast(const float* __restrict__ W, unsigned short* __restrict__ wp) {
    constexpr int NS = (8*CIN) / 32;
    constexpr int TOT = (O/16) * NS * 64;
    int t = blockIdx.x * 256 + threadIdx.x;
    if (t >= TOT) return;
    int l = t & 63;
    int s = (t >> 6) % NS;
    int ct = t / (64 * NS);
    int c = ct*16 + (l & 15);
    int kk0 = s*32 + (l >> 4) * 8;
    union { unsigned short u[8]; s8v v; } o;
    #pragma unroll
    for (int i = 0; i < 8; ++i) {
        int kk = kk0 + i;
        int h = kk / CIN, k = kk & (CIN - 1);
        o.u[i] = f2bf(W[(size_t)k*(8*O) + h*O + c]);
    }
    *(s8v*)(wp + (size_t)t*8) = o.v;
}

// ---------------- pack lin2 W (128 x 1024) ----------------
__global__ void packw_lin(const float* __restrict__ W, unsigned short* __restrict__ wp) {
    int t = blockIdx.x * 256 + threadIdx.x;
    if (t >= 64*4*64) return;
    int l = t & 63;
    int s = (t >> 6) & 3;
    int ctg = t >> 8;
    int c = ctg*16 + (l & 15);
    int k0 = s*32 + (l >> 4) * 8;
    union { unsigned short u[8]; s8v v; } o;
    #pragma unroll
    for (int i = 0; i < 8; ++i) o.u[i] = f2bf(W[(size_t)(k0+i)*1024 + c]);
    *(s8v*)(wp + (size_t)t*8) = o.v;
}

// ---------------- feast GEMM: hout = relu(g @ Wp / cnt + b) ----------------
template<int K, int O>
__global__ __launch_bounds__(256) void gemm_feast(
        const unsigned short* __restrict__ g, const unsigned short* __restrict__ wp,
        const int* __restrict__ rowptr, const float* __restrict__ b,
        float* __restrict__ hout) {
    constexpr int NS = K / 32;
    const int l = threadIdx.x & 63;
    const int w = threadIdx.x >> 6;
    const int base = blockIdx.x * 64 + w * 16;
    int arow = base + (l & 15); if (arow >= NN) arow = NN - 1;
    const int koff = (l >> 4) * 8;
    s8v af[NS];
    #pragma unroll
    for (int s = 0; s < NS; ++s)
        af[s] = *(const s8v*)(g + (size_t)arow*K + s*32 + koff);
    float invc[4];
    #pragma unroll
    for (int r = 0; r < 4; ++r) {
        int n = base + (l >> 4)*4 + r; if (n >= NN) n = NN - 1;
        invc[r] = 1.f / (float)(rowptr[n+1] - rowptr[n] + 1);
    }
    #pragma unroll 1
    for (int ct = 0; ct < O/16; ++ct) {
        f4v acc = {0.f, 0.f, 0.f, 0.f};
        #pragma unroll
        for (int s = 0; s < NS; ++s) {
            s8v bf = *(const s8v*)(wp + ((size_t)(ct*NS + s)*64 + l)*8);
            acc = __builtin_amdgcn_mfma_f32_16x16x32_bf16(af[s], bf, acc, 0, 0, 0);
        }
        int col = ct*16 + (l & 15);
        float bb = b[col];
        #pragma unroll
        for (int r = 0; r < 4; ++r) {
            int n = base + (l >> 4)*4 + r;
            if (n < NN) hout[(size_t)n*O + col] = fmaxf(acc[r]*invc[r] + bb, 0.f);
        }
    }
}

// ---------------- fused lin2(relu)+lin3+sigmoid via MFMA ----------------
__global__ __launch_bounds__(256) void lin23_mfma(
        const unsigned short* __restrict__ h4b, const unsigned short* __restrict__ w2p,
        const float* __restrict__ b2, const float* __restrict__ w3,
        const float* __restrict__ b3, float* __restrict__ p) {
    __shared__ float zred[64];
    const int l = threadIdx.x & 63;
    const int w = threadIdx.x >> 6;
    const int base = blockIdx.x * 16;
    const int arow = base + (l & 15);
    const int koff = (l >> 4) * 8;
    s8v af[4];
    #pragma unroll
    for (int s = 0; s < 4; ++s)
        af[s] = *(const s8v*)(h4b + (size_t)arow*128 + s*32 + koff);
    float zp0 = 0.f, zp1 = 0.f, zp2 = 0.f, zp3 = 0.f;
    #pragma unroll 1
    for (int ct = 0; ct < 16; ++ct) {
        f4v acc = {0.f, 0.f, 0.f, 0.f};
        #pragma unroll
        for (int s = 0; s < 4; ++s) {
            s8v bf = *(const s8v*)(w2p + ((size_t)((w*16 + ct)*4 + s)*64 + l)*8);
            acc = __builtin_amdgcn_mfma_f32_16x16x32_bf16(af[s], bf, acc, 0, 0, 0);
        }
        int col = w*256 + ct*16 + (l & 15);
        float w3c = w3[col], bb = b2[col];
        zp0 += fmaxf(acc[0] + bb, 0.f) * w3c;
        zp1 += fmaxf(acc[1] + bb, 0.f) * w3c;
        zp2 += fmaxf(acc[2] + bb, 0.f) * w3c;
        zp3 += fmaxf(acc[3] + bb, 0.f) * w3c;
    }
    #pragma unroll
    for (int off = 1; off < 16; off <<= 1) {
        zp0 += __shfl_xor(zp0, off, 64);
        zp1 += __shfl_xor(zp1, off, 64);
        zp2 += __shfl_xor(zp2, off, 64);
        zp3 += __shfl_xor(zp3, off, 64);
    }
    if ((l & 15) == 0) {
        int t = (l >> 4) * 4;
        zred[w*16 + t+0] = zp0; zred[w*16 + t+1] = zp1;
        zred[w*16 + t+2] = zp2; zred[w*16 + t+3] = zp3;
    }
    __syncthreads();
    if (threadIdx.x < 16) {
        float z = zred[threadIdx.x] + zred[16 + threadIdx.x]
                + zred[32 + threadIdx.x] + zred[48 + threadIdx.x] + b3[0];
        p[base + threadIdx.x] = 1.f / (1.f + expf(-z));
    }
}

// ---------------- f32 -> bf16 convert (N*128) ----------------
__global__ void cvt_kernel(const float* __restrict__ in, unsigned short* __restrict__ out) {
    int i = blockIdx.x * 256 + threadIdx.x;
    if (i >= NN * 32) return;      // NN*128/4
    float4 v = ((const float4*)in)[i];
    ushort4 o;
    o.x = f2bf(v.x); o.y = f2bf(v.y); o.z = f2bf(v.z); o.w = f2bf(v.w);
    ((ushort4*)out)[i] = o;
}

// ---------------- loss ----------------
__global__ void loss_pass_kernel(const float* __restrict__ labels,
                                 const float* __restrict__ p,
                                 float* __restrict__ scal) {
    __shared__ float sh0[256], sh1[256], sh2[256];
    int tid = threadIdx.x;
    float pos = 0.f, sp = 0.f, sn = 0.f;
    for (int n = blockIdx.x*256 + tid; n < NN; n += gridDim.x*256) {
        float yv = labels[n], pv = p[n];
        if (yv == 1.0f) { pos += 1.f; sp -= fmaxf(logf(pv), -100.f); }
        else            { sn -= fmaxf(logf(1.f - pv), -100.f); }
    }
    sh0[tid] = pos; sh1[tid] = sp; sh2[tid] = sn;
    __syncthreads();
    for (int off = 128; off; off >>= 1) {
        if (tid < off) {
            sh0[tid] += sh0[tid+off];
            sh1[tid] += sh1[tid+off];
            sh2[tid] += sh2[tid+off];
        }
        __syncthreads();
    }
    if (tid == 0) {
        atomicAdd(&scal[0], sh0[0]);
        atomicAdd(&scal[1], sh1[0]);
        atomicAdd(&scal[2], sh2[0]);
    }
}

__global__ void loss_final_kernel(const float* __restrict__ scal,
                                  float* __restrict__ out) {
    float pos = scal[0];
    out[0] = scal[1] / (2.f*pos) + scal[2] / (2.f*((float)NN - pos));
}

// ---------------- launch ----------------
extern "C" void kernel_launch(void* const* d_in, const int* in_sizes, int n_in,
                              void* d_out, int out_size, void* d_ws, size_t ws_size,
                              hipStream_t stream) {
    (void)in_sizes; (void)n_in; (void)out_size; (void)ws_size;
    const float* x   = (const float*)d_in[0];
    const int*   ei  = (const int*)d_in[1];
    const float* labels = (const float*)d_in[2];
    const float* l1w = (const float*)d_in[3];
    const float* l1b = (const float*)d_in[4];
    const float* cw[3] = {(const float*)d_in[5], (const float*)d_in[9],  (const float*)d_in[13]};
    const float* cu[3] = {(const float*)d_in[6], (const float*)d_in[10], (const float*)d_in[14]};
    const float* cc[3] = {(const float*)d_in[7], (const float*)d_in[11], (const float*)d_in[15]};
    const float* cb[3] = {(const float*)d_in[8], (const float*)d_in[12], (const float*)d_in[16]};
    const float* l2w = (const float*)d_in[17];
    const float* l2b = (const float*)d_in[18];
    const float* l3w = (const float*)d_in[19];
    const float* l3b = (const float*)d_in[20];
    const int* srcp = ei;
    const int* dstp = ei + NE;
    float* out = (float*)d_out;

    // ---- workspace (float units, 64B aligned) : total ~94 MB ----
    float* ws = (float*)d_ws;
    size_t off = 0;
    auto alloc = [&](size_t n) { float* p = ws + off; off += (n + 15) & ~(size_t)15; return p; };
    float* hA = alloc((size_t)NN*64);                 // h1(N,16) then h3(N,64)
    float* hB = alloc((size_t)NN*128);                // h2(N,32) then h4(N,128)
    float* a  = alloc((size_t)NN*8);
    unsigned short* g  = (unsigned short*)alloc((size_t)NN*256);  // N x 512 bf16 max
    unsigned short* w2p = (unsigned short*)alloc(65536);
    unsigned short* wfp = (unsigned short*)alloc(32768);
    float* sc   = alloc(16);
    float* scal = alloc(16);
    int* rowptr = (int*)alloc(50016);
    int* fill   = (int*)alloc(50000);
    int* ssrc   = (int*)alloc(NE);
    int* sdst   = (int*)alloc(NE);
    int* bpart  = (int*)alloc(256);
    unsigned short* h4b = g;                          // reuse g after conv3 GEMM
    // qs (NE*8 floats) aliases the conv output buffer (dead until its GEMM):
    float* qs1 = hB;      // conv1 out = hB
    float* qs2 = hA;      // conv2 out = hA (h1 dead by then)
    float* qs3 = hB;      // conv3 out = hB (h2 dead by then)

    const int SCAN_BLKS = (NN + 255) / 256;           // 196

    // ---- CSR build ----
    hipMemsetAsync(fill, 0, NN*sizeof(int), stream);
    hist_kernel<<<(NE+255)/256, 256, 0, stream>>>(dstp, fill);
    scan1_kernel<<<SCAN_BLKS, 256, 0, stream>>>(fill, rowptr, bpart);
    scan2_kernel<<<1, 256, 0, stream>>>(bpart, SCAN_BLKS);
    scan3_kernel<<<SCAN_BLKS, 256, 0, stream>>>(rowptr, bpart);
    hipMemsetAsync(fill, 0, NN*sizeof(int), stream);
    scatter_kernel<<<(NE+255)/256, 256, 0, stream>>>(srcp, dstp, rowptr, fill, ssrc, sdst);

    // ---- lin1 ----
    lin1_kernel<<<(NN*16+255)/256, 256, 0, stream>>>(x, l1w, l1b, hA);

    // ---- conv1: cin=16 -> O=32 (hA -> hB) ----
    sc_kernel<<<1, 1, 0, stream>>>(cc[0], sc);
    a_kernel<16><<<(NN*8+255)/256, 256, 0, stream>>>(hA, cu[0], a);
    q_sorted_kernel<<<(NE+255)/256, 256, 0, stream>>>(ssrc, sdst, a, cc[0], qs1);
    agg_kernel<16><<<NN/4, 256, 0, stream>>>(hA, sc, rowptr, ssrc, qs1, g);
    packw_feast<16,32><<<2, 256, 0, stream>>>(cw[0], wfp);
    gemm_feast<128,32><<<(NN+63)/64, 256, 0, stream>>>(g, wfp, rowptr, cb[0], hB);

    // ---- conv2: cin=32 -> O=64 (hB -> hA) ----
    sc_kernel<<<1, 1, 0, stream>>>(cc[1], sc);
    a_kernel<32><<<(NN*8+255)/256, 256, 0, stream>>>(hB, cu[1], a);
    q_sorted_kernel<<<(NE+255)/256, 256, 0, stream>>>(ssrc, sdst, a, cc[1], qs2);
    agg_kernel<32><<<NN/4, 256, 0, stream>>>(hB, sc, rowptr, ssrc, qs2, g);
    packw_feast<32,64><<<8, 256, 0, stream>>>(cw[1], wfp);
    gemm_feast<256,64><<<(NN+63)/64, 256, 0, stream>>>(g, wfp, rowptr, cb[1], hA);

    // ---- conv3: cin=64 -> O=128 (hA -> hB) ----
    sc_kernel<<<1, 1, 0, stream>>>(cc[2], sc);
    a_kernel<64><<<(NN*8+255)/256, 256, 0, stream>>>(hA, cu[2], a);
    q_sorted_kernel<<<(NE+255)/256, 256, 0, stream>>>(ssrc, sdst, a, cc[2], qs3);
    agg_kernel<64><<<NN/4, 256, 0, stream>>>(hA, sc, rowptr, ssrc, qs3, g);
    packw_feast<64,128><<<32, 256, 0, stream>>>(cw[2], wfp);
    gemm_feast<512,128><<<(NN+63)/64, 256, 0, stream>>>(g, wfp, rowptr, cb[2], hB);

    // ---- lin2+lin3+sigmoid ----
    cvt_kernel<<<(NN*32+255)/256, 256, 0, stream>>>(hB, h4b);
    packw_lin<<<64, 256, 0, stream>>>(l2w, w2p);
    lin23_mfma<<<NN/16, 256, 0, stream>>>(h4b, w2p, l2b, l3w, l3b, out + 1);

    // ---- loss ----
    hipMemsetAsync(scal, 0, 16*sizeof(float), stream);
    loss_pass_kernel<<<256, 256, 0, stream>>>(labels, out + 1, scal);
    loss_final_kernel<<<1, 1, 0, stream>>>(scal, out);
}

// Round 7
// 283.126 us; speedup vs baseline: 19.4290x; 1.1471x over previous
//
#include <hip/hip_runtime.h>
#include <math.h>

#define NN 50000
#define NE 300000

typedef short s8v __attribute__((ext_vector_type(8)));
typedef float f4v __attribute__((ext_vector_type(4)));

__device__ inline unsigned short f2bf(float f) {
    union { float f; unsigned int u; } v; v.f = f;
    unsigned int r = v.u + 0x7FFFu + ((v.u >> 16) & 1u);
    return (unsigned short)(r >> 16);
}

// ---------------- lin1: hA = relu(x @ W(3,16) + b) ----------------
__global__ void lin1_kernel(const float* __restrict__ x,
                            const float* __restrict__ w,
                            const float* __restrict__ b,
                            float* __restrict__ out) {
    int idx = blockIdx.x * 256 + threadIdx.x;
    if (idx >= NN * 16) return;
    int n = idx >> 4, o = idx & 15;
    float v = x[n*3+0]*w[o] + x[n*3+1]*w[16+o] + x[n*3+2]*w[32+o] + b[o];
    out[idx] = fmaxf(v, 0.f);
}

// ---------------- a = h @ u  (N x 8) ----------------
template<int CIN>
__global__ void a_kernel(const float* __restrict__ h,
                         const float* __restrict__ u,
                         float* __restrict__ a) {
    int idx = blockIdx.x * 256 + threadIdx.x;
    if (idx >= NN * 8) return;
    int n = idx >> 3, hd = idx & 7;
    float acc = 0.f;
    #pragma unroll
    for (int k = 0; k < CIN; ++k) acc += h[(size_t)n*CIN + k] * u[k*8 + hd];
    a[idx] = acc;
}

// ---------------- CSR build ----------------
__global__ void hist_kernel(const int* __restrict__ dst, int* __restrict__ cnt) {
    int e = blockIdx.x * 256 + threadIdx.x;
    if (e < NE) atomicAdd(&cnt[dst[e]], 1);
}

__global__ void scan1_kernel(const int* __restrict__ cnt, int* __restrict__ rp,
                             int* __restrict__ bpart) {
    __shared__ int sh[256];
    int tid = threadIdx.x;
    int gid = blockIdx.x * 256 + tid;
    int v = (gid < NN) ? cnt[gid] : 0;
    sh[tid] = v;
    __syncthreads();
    for (int off = 1; off < 256; off <<= 1) {
        int t = (tid >= off) ? sh[tid - off] : 0;
        __syncthreads();
        sh[tid] += t;
        __syncthreads();
    }
    if (gid < NN) rp[gid] = sh[tid] - v;            // exclusive
    if (tid == 255) bpart[blockIdx.x] = sh[tid];    // block total
}

__global__ void scan2_kernel(int* __restrict__ bpart, int nblk) {
    __shared__ int sh[256];
    int tid = threadIdx.x;
    int v = (tid < nblk) ? bpart[tid] : 0;
    sh[tid] = v;
    __syncthreads();
    for (int off = 1; off < 256; off <<= 1) {
        int t = (tid >= off) ? sh[tid - off] : 0;
        __syncthreads();
        sh[tid] += t;
        __syncthreads();
    }
    bpart[tid] = sh[tid] - v;                        // exclusive
}

__global__ void scan3_kernel(int* __restrict__ rp, const int* __restrict__ bpart) {
    int gid = blockIdx.x * 256 + threadIdx.x;
    if (gid < NN) rp[gid] += bpart[blockIdx.x];
    if (gid == 0) rp[NN] = NE;
}

__global__ void scatter_kernel(const int* __restrict__ src, const int* __restrict__ dst,
                               const int* __restrict__ rp, int* __restrict__ fill,
                               int* __restrict__ ssrc, int* __restrict__ sdst) {
    int e = blockIdx.x * 256 + threadIdx.x;
    if (e >= NE) return;
    int d = dst[e];
    int pos = rp[d] + atomicAdd(&fill[d], 1);
    ssrc[pos] = src[e];
    sdst[pos] = d;
}

// ---------------- q over sorted edges: qs[j,h] = softmax_h(a[s]-a[d]+c) ----
__global__ void q_sorted_kernel(const int* __restrict__ ssrc,
                                const int* __restrict__ sdst,
                                const float* __restrict__ a,
                                const float* __restrict__ c,
                                float* __restrict__ qs) {
    int j = blockIdx.x * 256 + threadIdx.x;
    if (j >= NE) return;
    int s = ssrc[j], d = sdst[j];
    const float4* as = (const float4*)(a + (size_t)s*8);
    const float4* ad = (const float4*)(a + (size_t)d*8);
    float4 s0 = as[0], s1 = as[1], d0 = ad[0], d1 = ad[1];
    float lg[8] = { s0.x-d0.x+c[0], s0.y-d0.y+c[1], s0.z-d0.z+c[2], s0.w-d0.w+c[3],
                    s1.x-d1.x+c[4], s1.y-d1.y+c[5], s1.z-d1.z+c[6], s1.w-d1.w+c[7] };
    float m = lg[0];
    #pragma unroll
    for (int h = 1; h < 8; ++h) m = fmaxf(m, lg[h]);
    float sum = 0.f;
    #pragma unroll
    for (int h = 0; h < 8; ++h) { lg[h] = __expf(lg[h]-m); sum += lg[h]; }
    float inv = 1.f / sum;
    float4* qp = (float4*)(qs + (size_t)j*8);
    qp[0] = make_float4(lg[0]*inv, lg[1]*inv, lg[2]*inv, lg[3]*inv);
    qp[1] = make_float4(lg[4]*inv, lg[5]*inv, lg[6]*inv, lg[7]*inv);
}

// ---------------- agg: g[d,h,k] = sc[h]*x[d,k] + sum_edges qs[j,h]*x[s,k] --
template<int HPER>
__device__ inline void load_qv(const float* __restrict__ qs, int j, int hg, float* qv) {
    if constexpr (HPER == 2) {
        float2 t = *(const float2*)(qs + (size_t)j*8 + hg*2);
        qv[0] = t.x; qv[1] = t.y;
    } else if constexpr (HPER == 4) {
        float4 t = *(const float4*)(qs + (size_t)j*8 + hg*4);
        qv[0] = t.x; qv[1] = t.y; qv[2] = t.z; qv[3] = t.w;
    } else {
        float4 t0 = *(const float4*)(qs + (size_t)j*8);
        float4 t1 = *(const float4*)(qs + (size_t)j*8 + 4);
        qv[0] = t0.x; qv[1] = t0.y; qv[2] = t0.z; qv[3] = t0.w;
        qv[4] = t1.x; qv[5] = t1.y; qv[6] = t1.z; qv[7] = t1.w;
    }
}

template<int CIN>
__global__ __launch_bounds__(256) void agg_kernel(
        const float* __restrict__ hin, const float* __restrict__ cbias,
        const int* __restrict__ rowptr, const int* __restrict__ ssrc,
        const float* __restrict__ qs, unsigned short* __restrict__ g) {
    constexpr int HPER = CIN / 8;                 // 2,4,8
    constexpr int LG = (CIN == 16) ? 4 : (CIN == 32) ? 5 : 6;
    const int lane = threadIdx.x & 63;
    const int d = blockIdx.x * 4 + (threadIdx.x >> 6);
    const int k = lane & (CIN - 1);
    const int hg = lane >> LG;                    // head-group of this lane
    // sc = softmax(cbias), only the HPER entries this lane needs
    float m = cbias[0];
    #pragma unroll
    for (int h = 1; h < 8; ++h) m = fmaxf(m, cbias[h]);
    float ssum = 0.f;
    #pragma unroll
    for (int h = 0; h < 8; ++h) ssum += __expf(cbias[h] - m);
    float sinv = 1.f / ssum;
    float xd = hin[(size_t)d*CIN + k];
    float acc[HPER];
    #pragma unroll
    for (int i = 0; i < HPER; ++i)
        acc[i] = __expf(cbias[hg*HPER + i] - m) * sinv * xd;
    int j0 = rowptr[d], j1 = rowptr[d+1];
    int j = j0;
    for (; j + 2 <= j1; j += 2) {                 // 2 independent gather chains
        int s0 = ssrc[j], s1 = ssrc[j+1];
        float xv0 = hin[(size_t)s0*CIN + k];
        float xv1 = hin[(size_t)s1*CIN + k];
        float qv0[HPER], qv1[HPER];
        load_qv<HPER>(qs, j, hg, qv0);
        load_qv<HPER>(qs, j+1, hg, qv1);
        #pragma unroll
        for (int i = 0; i < HPER; ++i) acc[i] += qv0[i]*xv0 + qv1[i]*xv1;
    }
    if (j < j1) {
        int s0 = ssrc[j];
        float xv0 = hin[(size_t)s0*CIN + k];
        float qv0[HPER];
        load_qv<HPER>(qs, j, hg, qv0);
        #pragma unroll
        for (int i = 0; i < HPER; ++i) acc[i] += qv0[i]*xv0;
    }
    #pragma unroll
    for (int i = 0; i < HPER; ++i)
        g[(size_t)d*(8*CIN) + (hg*HPER + i)*CIN + k] = f2bf(acc[i]);
}

// ---------------- pack feast W into B-frag order ----------------
template<int CIN, int O>
__global__ void packw_feast(const float* __restrict__ W, unsigned short* __restrict__ wp) {
    constexpr int NS = (8*CIN) / 32;
    constexpr int TOT = (O/16) * NS * 64;
    int t = blockIdx.x * 256 + threadIdx.x;
    if (t >= TOT) return;
    int l = t & 63;
    int s = (t >> 6) % NS;
    int ct = t / (64 * NS);
    int c = ct*16 + (l & 15);
    int kk0 = s*32 + (l >> 4) * 8;
    union { unsigned short u[8]; s8v v; } o;
    #pragma unroll
    for (int i = 0; i < 8; ++i) {
        int kk = kk0 + i;
        int h = kk / CIN, k = kk & (CIN - 1);
        o.u[i] = f2bf(W[(size_t)k*(8*O) + h*O + c]);
    }
    *(s8v*)(wp + (size_t)t*8) = o.v;
}

// ---------------- pack lin2 W (128 x 1024) ----------------
__global__ void packw_lin(const float* __restrict__ W, unsigned short* __restrict__ wp) {
    int t = blockIdx.x * 256 + threadIdx.x;
    if (t >= 64*4*64) return;
    int l = t & 63;
    int s = (t >> 6) & 3;
    int ctg = t >> 8;
    int c = ctg*16 + (l & 15);
    int k0 = s*32 + (l >> 4) * 8;
    union { unsigned short u[8]; s8v v; } o;
    #pragma unroll
    for (int i = 0; i < 8; ++i) o.u[i] = f2bf(W[(size_t)(k0+i)*1024 + c]);
    *(s8v*)(wp + (size_t)t*8) = o.v;
}

// ---------------- feast GEMM: hout = relu(g @ Wp / cnt + b) ----------------
// 64 rows/block (4 waves x 16 rows), B staged in LDS chunks of CH ct-tiles.
template<int K, int O, int CH, bool BF16OUT>
__global__ __launch_bounds__(256) void gemm_feast(
        const unsigned short* __restrict__ g, const unsigned short* __restrict__ wp,
        const int* __restrict__ rowptr, const float* __restrict__ b,
        float* __restrict__ houtf, unsigned short* __restrict__ houtb) {
    constexpr int NS = K / 32;
    constexpr int NCT = O / 16;
    __shared__ unsigned short bsh[CH*NS*64*8];
    const int l = threadIdx.x & 63;
    const int w = threadIdx.x >> 6;
    const int base = blockIdx.x * 64 + w * 16;
    int arow = base + (l & 15); if (arow >= NN) arow = NN - 1;
    const int koff = (l >> 4) * 8;
    s8v af[NS];
    #pragma unroll
    for (int s = 0; s < NS; ++s)
        af[s] = *(const s8v*)(g + (size_t)arow*K + s*32 + koff);
    float invc[4];
    #pragma unroll
    for (int r = 0; r < 4; ++r) {
        int n = base + (l >> 4)*4 + r; if (n >= NN) n = NN - 1;
        invc[r] = 1.f / (float)(rowptr[n+1] - rowptr[n] + 1);
    }
    #pragma unroll 1
    for (int ct0 = 0; ct0 < NCT; ct0 += CH) {
        __syncthreads();
        const int4* sp = (const int4*)(wp + (size_t)ct0*NS*512);
        int4* dp = (int4*)bsh;
        #pragma unroll 1
        for (int i = threadIdx.x; i < CH*NS*64; i += 256) dp[i] = sp[i];
        __syncthreads();
        #pragma unroll 1
        for (int cc = 0; cc < CH; ++cc) {
            f4v acc = {0.f, 0.f, 0.f, 0.f};
            #pragma unroll
            for (int s = 0; s < NS; ++s) {
                s8v bf = *(const s8v*)(bsh + ((size_t)(cc*NS + s)*64 + l)*8);
                acc = __builtin_amdgcn_mfma_f32_16x16x32_bf16(af[s], bf, acc, 0, 0, 0);
            }
            int col = (ct0 + cc)*16 + (l & 15);
            float bb = b[col];
            #pragma unroll
            for (int r = 0; r < 4; ++r) {
                int n = base + (l >> 4)*4 + r;
                float v = fmaxf(acc[r]*invc[r] + bb, 0.f);
                if (n < NN) {
                    if constexpr (BF16OUT) houtb[(size_t)n*O + col] = f2bf(v);
                    else                   houtf[(size_t)n*O + col] = v;
                }
            }
        }
    }
}

// ---------------- fused lin2(relu)+lin3+sigmoid via MFMA ----------------
// 64 rows/block (4 waves x 16 rows); each wave covers ALL 64 ct-tiles for its
// rows, B staged in LDS chunks of 8 ct-tiles (32 KB) -> B read once per block.
__global__ __launch_bounds__(256) void lin23_mfma(
        const unsigned short* __restrict__ h4b, const unsigned short* __restrict__ w2p,
        const float* __restrict__ b2, const float* __restrict__ w3,
        const float* __restrict__ b3, float* __restrict__ p) {
    constexpr int CH = 8;
    __shared__ unsigned short bsh[CH*4*64*8];     // 32 KB
    const int l = threadIdx.x & 63;
    const int w = threadIdx.x >> 6;
    const int base = blockIdx.x * 64 + w * 16;
    int arow = base + (l & 15); if (arow >= NN) arow = NN - 1;
    const int koff = (l >> 4) * 8;
    s8v af[4];
    #pragma unroll
    for (int s = 0; s < 4; ++s)
        af[s] = *(const s8v*)(h4b + (size_t)arow*128 + s*32 + koff);
    float zp0 = 0.f, zp1 = 0.f, zp2 = 0.f, zp3 = 0.f;
    #pragma unroll 1
    for (int ct0 = 0; ct0 < 64; ct0 += CH) {
        __syncthreads();
        const int4* sp = (const int4*)(w2p + (size_t)ct0*4*512);
        int4* dp = (int4*)bsh;
        #pragma unroll 1
        for (int i = threadIdx.x; i < CH*4*64; i += 256) dp[i] = sp[i];
        __syncthreads();
        #pragma unroll 1
        for (int cc = 0; cc < CH; ++cc) {
            f4v acc = {0.f, 0.f, 0.f, 0.f};
            #pragma unroll
            for (int s = 0; s < 4; ++s) {
                s8v bf = *(const s8v*)(bsh + ((size_t)(cc*4 + s)*64 + l)*8);
                acc = __builtin_amdgcn_mfma_f32_16x16x32_bf16(af[s], bf, acc, 0, 0, 0);
            }
            int col = (ct0 + cc)*16 + (l & 15);
            float w3c = w3[col], bb = b2[col];
            zp0 += fmaxf(acc[0] + bb, 0.f) * w3c;
            zp1 += fmaxf(acc[1] + bb, 0.f) * w3c;
            zp2 += fmaxf(acc[2] + bb, 0.f) * w3c;
            zp3 += fmaxf(acc[3] + bb, 0.f) * w3c;
        }
    }
    #pragma unroll
    for (int off = 1; off < 16; off <<= 1) {
        zp0 += __shfl_xor(zp0, off, 64);
        zp1 += __shfl_xor(zp1, off, 64);
        zp2 += __shfl_xor(zp2, off, 64);
        zp3 += __shfl_xor(zp3, off, 64);
    }
    if ((l & 15) == 0) {
        int r0 = base + (l >> 4) * 4;
        float bb3 = b3[0];
        if (r0+0 < NN) p[r0+0] = 1.f / (1.f + expf(-(zp0 + bb3)));
        if (r0+1 < NN) p[r0+1] = 1.f / (1.f + expf(-(zp1 + bb3)));
        if (r0+2 < NN) p[r0+2] = 1.f / (1.f + expf(-(zp2 + bb3)));
        if (r0+3 < NN) p[r0+3] = 1.f / (1.f + expf(-(zp3 + bb3)));
    }
}

// ---------------- loss ----------------
__global__ void loss_pass_kernel(const float* __restrict__ labels,
                                 const float* __restrict__ p,
                                 float* __restrict__ scal) {
    __shared__ float sh0[256], sh1[256], sh2[256];
    int tid = threadIdx.x;
    float pos = 0.f, sp = 0.f, sn = 0.f;
    for (int n = blockIdx.x*256 + tid; n < NN; n += gridDim.x*256) {
        float yv = labels[n], pv = p[n];
        if (yv == 1.0f) { pos += 1.f; sp -= fmaxf(logf(pv), -100.f); }
        else            { sn -= fmaxf(logf(1.f - pv), -100.f); }
    }
    sh0[tid] = pos; sh1[tid] = sp; sh2[tid] = sn;
    __syncthreads();
    for (int off = 128; off; off >>= 1) {
        if (tid < off) {
            sh0[tid] += sh0[tid+off];
            sh1[tid] += sh1[tid+off];
            sh2[tid] += sh2[tid+off];
        }
        __syncthreads();
    }
    if (tid == 0) {
        atomicAdd(&scal[0], sh0[0]);
        atomicAdd(&scal[1], sh1[0]);
        atomicAdd(&scal[2], sh2[0]);
    }
}

__global__ void loss_final_kernel(const float* __restrict__ scal,
                                  float* __restrict__ out) {
    float pos = scal[0];
    out[0] = scal[1] / (2.f*pos) + scal[2] / (2.f*((float)NN - pos));
}

// ---------------- launch ----------------
extern "C" void kernel_launch(void* const* d_in, const int* in_sizes, int n_in,
                              void* d_out, int out_size, void* d_ws, size_t ws_size,
                              hipStream_t stream) {
    (void)in_sizes; (void)n_in; (void)out_size; (void)ws_size;
    const float* x   = (const float*)d_in[0];
    const int*   ei  = (const int*)d_in[1];
    const float* labels = (const float*)d_in[2];
    const float* l1w = (const float*)d_in[3];
    const float* l1b = (const float*)d_in[4];
    const float* cw[3] = {(const float*)d_in[5], (const float*)d_in[9],  (const float*)d_in[13]};
    const float* cu[3] = {(const float*)d_in[6], (const float*)d_in[10], (const float*)d_in[14]};
    const float* cc[3] = {(const float*)d_in[7], (const float*)d_in[11], (const float*)d_in[15]};
    const float* cb[3] = {(const float*)d_in[8], (const float*)d_in[12], (const float*)d_in[16]};
    const float* l2w = (const float*)d_in[17];
    const float* l2b = (const float*)d_in[18];
    const float* l3w = (const float*)d_in[19];
    const float* l3b = (const float*)d_in[20];
    const int* srcp = ei;
    const int* dstp = ei + NE;
    float* out = (float*)d_out;

    // ---- workspace (float units, 64B aligned) : total ~94 MB ----
    float* ws = (float*)d_ws;
    size_t off = 0;
    auto alloc = [&](size_t n) { float* p = ws + off; off += (n + 15) & ~(size_t)15; return p; };
    float* hA = alloc((size_t)NN*64);                 // h1(N,16) then h3(N,64)
    float* hB = alloc((size_t)NN*128);                // h2(N,32) then h4 (bf16)
    float* a  = alloc((size_t)NN*8);
    unsigned short* g  = (unsigned short*)alloc((size_t)NN*256);  // N x 512 bf16 max
    unsigned short* w2p = (unsigned short*)alloc(65536);
    unsigned short* wfp = (unsigned short*)alloc(32768);
    float* scal = alloc(16);
    int* rowptr = (int*)alloc(50016);
    int* fill   = (int*)alloc(50000);
    int* ssrc   = (int*)alloc(NE);
    int* sdst   = (int*)alloc(NE);
    int* bpart  = (int*)alloc(256);
    // qs (NE*8 floats) aliases the conv output buffer (dead until its GEMM):
    float* qs1 = hB;      // conv1 out = hB (f32)
    float* qs2 = hA;      // conv2 out = hA (f32)
    float* qs3 = hB;      // conv3 out = hB (bf16, overwrites dead qs3)
    unsigned short* h4b = (unsigned short*)hB;

    const int SCAN_BLKS = (NN + 255) / 256;           // 196
    const int GB = (NN + 63) / 64;                    // 782 row-blocks

    // ---- CSR build ----
    hipMemsetAsync(fill, 0, NN*sizeof(int), stream);
    hist_kernel<<<(NE+255)/256, 256, 0, stream>>>(dstp, fill);
    scan1_kernel<<<SCAN_BLKS, 256, 0, stream>>>(fill, rowptr, bpart);
    scan2_kernel<<<1, 256, 0, stream>>>(bpart, SCAN_BLKS);
    scan3_kernel<<<SCAN_BLKS, 256, 0, stream>>>(rowptr, bpart);
    hipMemsetAsync(fill, 0, NN*sizeof(int), stream);
    scatter_kernel<<<(NE+255)/256, 256, 0, stream>>>(srcp, dstp, rowptr, fill, ssrc, sdst);

    // ---- lin1 ----
    lin1_kernel<<<(NN*16+255)/256, 256, 0, stream>>>(x, l1w, l1b, hA);

    // ---- conv1: cin=16 -> O=32 (hA -> hB f32) ----
    a_kernel<16><<<(NN*8+255)/256, 256, 0, stream>>>(hA, cu[0], a);
    q_sorted_kernel<<<(NE+255)/256, 256, 0, stream>>>(ssrc, sdst, a, cc[0], qs1);
    agg_kernel<16><<<NN/4, 256, 0, stream>>>(hA, cc[0], rowptr, ssrc, qs1, g);
    packw_feast<16,32><<<2, 256, 0, stream>>>(cw[0], wfp);
    gemm_feast<128,32,2,false><<<GB, 256, 0, stream>>>(g, wfp, rowptr, cb[0], hB, nullptr);

    // ---- conv2: cin=32 -> O=64 (hB -> hA f32) ----
    a_kernel<32><<<(NN*8+255)/256, 256, 0, stream>>>(hB, cu[1], a);
    q_sorted_kernel<<<(NE+255)/256, 256, 0, stream>>>(ssrc, sdst, a, cc[1], qs2);
    agg_kernel<32><<<NN/4, 256, 0, stream>>>(hB, cc[1], rowptr, ssrc, qs2, g);
    packw_feast<32,64><<<8, 256, 0, stream>>>(cw[1], wfp);
    gemm_feast<256,64,4,false><<<GB, 256, 0, stream>>>(g, wfp, rowptr, cb[1], hA, nullptr);

    // ---- conv3: cin=64 -> O=128 (hA -> hB bf16 direct) ----
    a_kernel<64><<<(NN*8+255)/256, 256, 0, stream>>>(hA, cu[2], a);
    q_sorted_kernel<<<(NE+255)/256, 256, 0, stream>>>(ssrc, sdst, a, cc[2], qs3);
    agg_kernel<64><<<NN/4, 256, 0, stream>>>(hA, cc[2], rowptr, ssrc, qs3, g);
    packw_feast<64,128><<<32, 256, 0, stream>>>(cw[2], wfp);
    gemm_feast<512,128,2,true><<<GB, 256, 0, stream>>>(g, wfp, rowptr, cb[2], nullptr, h4b);

    // ---- lin2+lin3+sigmoid ----
    packw_lin<<<64, 256, 0, stream>>>(l2w, w2p);
    lin23_mfma<<<GB, 256, 0, stream>>>(h4b, w2p, l2b, l3w, l3b, out + 1);

    // ---- loss ----
    hipMemsetAsync(scal, 0, 16*sizeof(float), stream);
    loss_pass_kernel<<<256, 256, 0, stream>>>(labels, out + 1, scal);
    loss_final_kernel<<<1, 1, 0, stream>>>(scal, out);
}

// Round 8
// 271.200 us; speedup vs baseline: 20.2835x; 1.0440x over previous
//
#include <hip/hip_runtime.h>
#include <math.h>

#define NN 50000
#define NE 300000

typedef short s8v __attribute__((ext_vector_type(8)));
typedef float f4v __attribute__((ext_vector_type(4)));

__device__ inline unsigned short f2bf(float f) {
    union { float f; unsigned int u; } v; v.f = f;
    unsigned int r = v.u + 0x7FFFu + ((v.u >> 16) & 1u);
    return (unsigned short)(r >> 16);
}

// ---------------- lin1: hA = relu(x @ W(3,16) + b) ----------------
__global__ void lin1_kernel(const float* __restrict__ x,
                            const float* __restrict__ w,
                            const float* __restrict__ b,
                            float* __restrict__ out) {
    int idx = blockIdx.x * 256 + threadIdx.x;
    if (idx >= NN * 16) return;
    int n = idx >> 4, o = idx & 15;
    float v = x[n*3+0]*w[o] + x[n*3+1]*w[16+o] + x[n*3+2]*w[32+o] + b[o];
    out[idx] = fmaxf(v, 0.f);
}

// ---------------- a = h @ u  (N x 8) ----------------
template<int CIN>
__global__ void a_kernel(const float* __restrict__ h,
                         const float* __restrict__ u,
                         float* __restrict__ a) {
    int idx = blockIdx.x * 256 + threadIdx.x;
    if (idx >= NN * 8) return;
    int n = idx >> 3, hd = idx & 7;
    float acc = 0.f;
    #pragma unroll
    for (int k = 0; k < CIN; ++k) acc += h[(size_t)n*CIN + k] * u[k*8 + hd];
    a[idx] = acc;
}

// ---------------- CSR build ----------------
__global__ void hist_kernel(const int* __restrict__ dst, int* __restrict__ cnt) {
    int e = blockIdx.x * 256 + threadIdx.x;
    if (e < NE) atomicAdd(&cnt[dst[e]], 1);
}

__global__ void scan1_kernel(const int* __restrict__ cnt, int* __restrict__ rp,
                             int* __restrict__ bpart) {
    __shared__ int sh[256];
    int tid = threadIdx.x;
    int gid = blockIdx.x * 256 + tid;
    int v = (gid < NN) ? cnt[gid] : 0;
    sh[tid] = v;
    __syncthreads();
    for (int off = 1; off < 256; off <<= 1) {
        int t = (tid >= off) ? sh[tid - off] : 0;
        __syncthreads();
        sh[tid] += t;
        __syncthreads();
    }
    if (gid < NN) rp[gid] = sh[tid] - v;            // exclusive
    if (tid == 255) bpart[blockIdx.x] = sh[tid];    // block total
}

__global__ void scan2_kernel(int* __restrict__ bpart, int nblk) {
    __shared__ int sh[256];
    int tid = threadIdx.x;
    int v = (tid < nblk) ? bpart[tid] : 0;
    sh[tid] = v;
    __syncthreads();
    for (int off = 1; off < 256; off <<= 1) {
        int t = (tid >= off) ? sh[tid - off] : 0;
        __syncthreads();
        sh[tid] += t;
        __syncthreads();
    }
    bpart[tid] = sh[tid] - v;                        // exclusive
}

__global__ void scan3_kernel(int* __restrict__ rp, const int* __restrict__ bpart) {
    int gid = blockIdx.x * 256 + threadIdx.x;
    if (gid < NN) rp[gid] += bpart[blockIdx.x];
    if (gid == 0) rp[NN] = NE;
}

__global__ void scatter_kernel(const int* __restrict__ src, const int* __restrict__ dst,
                               const int* __restrict__ rp, int* __restrict__ fill,
                               int* __restrict__ ssrc, int* __restrict__ sdst) {
    int e = blockIdx.x * 256 + threadIdx.x;
    if (e >= NE) return;
    int d = dst[e];
    int pos = rp[d] + atomicAdd(&fill[d], 1);
    ssrc[pos] = src[e];
    sdst[pos] = d;
}

// ---------------- q over sorted edges ----------------
__global__ void q_sorted_kernel(const int* __restrict__ ssrc,
                                const int* __restrict__ sdst,
                                const float* __restrict__ a,
                                const float* __restrict__ c,
                                float* __restrict__ qs) {
    int j = blockIdx.x * 256 + threadIdx.x;
    if (j >= NE) return;
    int s = ssrc[j], d = sdst[j];
    const float4* as = (const float4*)(a + (size_t)s*8);
    const float4* ad = (const float4*)(a + (size_t)d*8);
    float4 s0 = as[0], s1 = as[1], d0 = ad[0], d1 = ad[1];
    float lg[8] = { s0.x-d0.x+c[0], s0.y-d0.y+c[1], s0.z-d0.z+c[2], s0.w-d0.w+c[3],
                    s1.x-d1.x+c[4], s1.y-d1.y+c[5], s1.z-d1.z+c[6], s1.w-d1.w+c[7] };
    float m = lg[0];
    #pragma unroll
    for (int h = 1; h < 8; ++h) m = fmaxf(m, lg[h]);
    float sum = 0.f;
    #pragma unroll
    for (int h = 0; h < 8; ++h) { lg[h] = __expf(lg[h]-m); sum += lg[h]; }
    float inv = 1.f / sum;
    float4* qp = (float4*)(qs + (size_t)j*8);
    qp[0] = make_float4(lg[0]*inv, lg[1]*inv, lg[2]*inv, lg[3]*inv);
    qp[1] = make_float4(lg[4]*inv, lg[5]*inv, lg[6]*inv, lg[7]*inv);
}

// ---------------- agg ----------------
template<int HPER>
__device__ inline void load_qv(const float* __restrict__ qs, int j, int hg, float* qv) {
    if constexpr (HPER == 2) {
        float2 t = *(const float2*)(qs + (size_t)j*8 + hg*2);
        qv[0] = t.x; qv[1] = t.y;
    } else if constexpr (HPER == 4) {
        float4 t = *(const float4*)(qs + (size_t)j*8 + hg*4);
        qv[0] = t.x; qv[1] = t.y; qv[2] = t.z; qv[3] = t.w;
    } else {
        float4 t0 = *(const float4*)(qs + (size_t)j*8);
        float4 t1 = *(const float4*)(qs + (size_t)j*8 + 4);
        qv[0] = t0.x; qv[1] = t0.y; qv[2] = t0.z; qv[3] = t0.w;
        qv[4] = t1.x; qv[5] = t1.y; qv[6] = t1.z; qv[7] = t1.w;
    }
}

template<int CIN>
__global__ __launch_bounds__(256) void agg_kernel(
        const float* __restrict__ hin, const float* __restrict__ cbias,
        const int* __restrict__ rowptr, const int* __restrict__ ssrc,
        const float* __restrict__ qs, unsigned short* __restrict__ g) {
    constexpr int HPER = CIN / 8;
    constexpr int LG = (CIN == 16) ? 4 : (CIN == 32) ? 5 : 6;
    const int lane = threadIdx.x & 63;
    const int d = blockIdx.x * 4 + (threadIdx.x >> 6);
    const int k = lane & (CIN - 1);
    const int hg = lane >> LG;
    float m = cbias[0];
    #pragma unroll
    for (int h = 1; h < 8; ++h) m = fmaxf(m, cbias[h]);
    float ssum = 0.f;
    #pragma unroll
    for (int h = 0; h < 8; ++h) ssum += __expf(cbias[h] - m);
    float sinv = 1.f / ssum;
    float xd = hin[(size_t)d*CIN + k];
    float acc[HPER];
    #pragma unroll
    for (int i = 0; i < HPER; ++i)
        acc[i] = __expf(cbias[hg*HPER + i] - m) * sinv * xd;
    int j0 = rowptr[d], j1 = rowptr[d+1];
    int j = j0;
    for (; j + 2 <= j1; j += 2) {
        int s0 = ssrc[j], s1 = ssrc[j+1];
        float xv0 = hin[(size_t)s0*CIN + k];
        float xv1 = hin[(size_t)s1*CIN + k];
        float qv0[HPER], qv1[HPER];
        load_qv<HPER>(qs, j, hg, qv0);
        load_qv<HPER>(qs, j+1, hg, qv1);
        #pragma unroll
        for (int i = 0; i < HPER; ++i) acc[i] += qv0[i]*xv0 + qv1[i]*xv1;
    }
    if (j < j1) {
        int s0 = ssrc[j];
        float xv0 = hin[(size_t)s0*CIN + k];
        float qv0[HPER];
        load_qv<HPER>(qs, j, hg, qv0);
        #pragma unroll
        for (int i = 0; i < HPER; ++i) acc[i] += qv0[i]*xv0;
    }
    #pragma unroll
    for (int i = 0; i < HPER; ++i)
        g[(size_t)d*(8*CIN) + (hg*HPER + i)*CIN + k] = f2bf(acc[i]);
}

// ---------------- weight pack bodies ----------------
template<int CIN, int O>
__device__ inline void packw_feast_body(const float* __restrict__ W,
                                        unsigned short* __restrict__ wp, int t) {
    constexpr int NS = (8*CIN) / 32;
    int l = t & 63;
    int s = (t >> 6) % NS;
    int ct = t / (64 * NS);
    int c = ct*16 + (l & 15);
    int kk0 = s*32 + (l >> 4) * 8;
    union { unsigned short u[8]; s8v v; } o;
    #pragma unroll
    for (int i = 0; i < 8; ++i) {
        int kk = kk0 + i;
        int h = kk / CIN, k = kk & (CIN - 1);
        o.u[i] = f2bf(W[(size_t)k*(8*O) + h*O + c]);
    }
    *(s8v*)(wp + (size_t)t*8) = o.v;
}

__device__ inline void packw_lin_body(const float* __restrict__ W,
                                      unsigned short* __restrict__ wp, int t) {
    int l = t & 63;
    int s = (t >> 6) & 3;
    int ctg = t >> 8;
    int c = ctg*16 + (l & 15);
    int k0 = s*32 + (l >> 4) * 8;
    union { unsigned short u[8]; s8v v; } o;
    #pragma unroll
    for (int i = 0; i < 8; ++i) o.u[i] = f2bf(W[(size_t)(k0+i)*1024 + c]);
    *(s8v*)(wp + (size_t)t*8) = o.v;
}

// ---------------- prep: all packs + buffer zeroing in ONE dispatch ----------
__global__ void prep_kernel(const float* __restrict__ l2w, unsigned short* __restrict__ w2p,
                            const float* __restrict__ wf1w, unsigned short* __restrict__ wf1,
                            const float* __restrict__ wf2w, unsigned short* __restrict__ wf2,
                            const float* __restrict__ wf3w, unsigned short* __restrict__ wf3,
                            int* __restrict__ fill, int* __restrict__ fill2,
                            float* __restrict__ z, float* __restrict__ scal) {
    int b = blockIdx.x;
    int tid = threadIdx.x;
    if (b < 64)  { packw_lin_body(l2w, w2p, b*256 + tid); return; }
    b -= 64;
    if (b < 2)   { packw_feast_body<16,32>(wf1w, wf1, b*256 + tid); return; }
    b -= 2;
    if (b < 8)   { packw_feast_body<32,64>(wf2w, wf2, b*256 + tid); return; }
    b -= 8;
    if (b < 32)  { packw_feast_body<64,128>(wf3w, wf3, b*256 + tid); return; }
    b -= 32;
    int idx = b*256 + tid;
    if (idx < NN)            fill[idx] = 0;
    else if (idx < 2*NN)     fill2[idx - NN] = 0;
    else if (idx < 3*NN)     z[idx - 2*NN] = 0.f;
    else if (idx < 3*NN+16)  scal[idx - 3*NN] = 0.f;
}

// ---------------- feast GEMM (split MFMA chains) ----------------
template<int K, int O, int CH, bool BF16OUT>
__global__ __launch_bounds__(256) void gemm_feast(
        const unsigned short* __restrict__ g, const unsigned short* __restrict__ wp,
        const int* __restrict__ rowptr, const float* __restrict__ b,
        float* __restrict__ houtf, unsigned short* __restrict__ houtb) {
    constexpr int NS = K / 32;
    constexpr int NCT = O / 16;
    __shared__ unsigned short bsh[CH*NS*64*8];
    const int l = threadIdx.x & 63;
    const int w = threadIdx.x >> 6;
    const int base = blockIdx.x * 64 + w * 16;
    int arow = base + (l & 15); if (arow >= NN) arow = NN - 1;
    const int koff = (l >> 4) * 8;
    s8v af[NS];
    #pragma unroll
    for (int s = 0; s < NS; ++s)
        af[s] = *(const s8v*)(g + (size_t)arow*K + s*32 + koff);
    float invc[4];
    #pragma unroll
    for (int r = 0; r < 4; ++r) {
        int n = base + (l >> 4)*4 + r; if (n >= NN) n = NN - 1;
        invc[r] = 1.f / (float)(rowptr[n+1] - rowptr[n] + 1);
    }
    #pragma unroll 1
    for (int ct0 = 0; ct0 < NCT; ct0 += CH) {
        __syncthreads();
        const int4* sp = (const int4*)(wp + (size_t)ct0*NS*512);
        int4* dp = (int4*)bsh;
        #pragma unroll 1
        for (int i = threadIdx.x; i < CH*NS*64; i += 256) dp[i] = sp[i];
        __syncthreads();
        #pragma unroll 1
        for (int cc = 0; cc < CH; ++cc) {
            f4v accA = {0.f,0.f,0.f,0.f}, accB = {0.f,0.f,0.f,0.f};
            #pragma unroll
            for (int s = 0; s < NS/2; ++s) {
                s8v bf = *(const s8v*)(bsh + ((size_t)(cc*NS + s)*64 + l)*8);
                accA = __builtin_amdgcn_mfma_f32_16x16x32_bf16(af[s], bf, accA, 0, 0, 0);
            }
            #pragma unroll
            for (int s = NS/2; s < NS; ++s) {
                s8v bf = *(const s8v*)(bsh + ((size_t)(cc*NS + s)*64 + l)*8);
                accB = __builtin_amdgcn_mfma_f32_16x16x32_bf16(af[s], bf, accB, 0, 0, 0);
            }
            int col = (ct0 + cc)*16 + (l & 15);
            float bb = b[col];
            #pragma unroll
            for (int r = 0; r < 4; ++r) {
                int n = base + (l >> 4)*4 + r;
                float v = fmaxf((accA[r]+accB[r])*invc[r] + bb, 0.f);
                if (n < NN) {
                    if constexpr (BF16OUT) houtb[(size_t)n*O + col] = f2bf(v);
                    else                   houtf[(size_t)n*O + col] = v;
                }
            }
        }
    }
}

// ---------------- lin23 as split-ct reduction: z += relu(h4@W2+b2)·w3 ------
// grid (196, 16): block = 4 waves x 64 rows = 256 rows, 4 ct-tiles per block.
// No LDS, no barriers; B-frags live in registers; z via atomicAdd.
__global__ __launch_bounds__(256) void lin23z_kernel(
        const unsigned short* __restrict__ h4b, const unsigned short* __restrict__ w2p,
        const float* __restrict__ b2, const float* __restrict__ w3,
        float* __restrict__ z) {
    const int l = threadIdx.x & 63;
    const int w = threadIdx.x >> 6;
    const int ctg = blockIdx.y;                       // 0..15 -> 4 ct each
    const int rowbase = blockIdx.x * 256 + w * 64;
    const int koff = (l >> 4) * 8;
    s8v bf0[4], bf1[4], bf2[4], bf3[4];
    #pragma unroll
    for (int s = 0; s < 4; ++s) {
        bf0[s] = *(const s8v*)(w2p + ((size_t)((ctg*4+0)*4 + s)*64 + l)*8);
        bf1[s] = *(const s8v*)(w2p + ((size_t)((ctg*4+1)*4 + s)*64 + l)*8);
        bf2[s] = *(const s8v*)(w2p + ((size_t)((ctg*4+2)*4 + s)*64 + l)*8);
        bf3[s] = *(const s8v*)(w2p + ((size_t)((ctg*4+3)*4 + s)*64 + l)*8);
    }
    float w3c[4], b2c[4];
    #pragma unroll
    for (int c = 0; c < 4; ++c) {
        int col = (ctg*4 + c)*16 + (l & 15);
        w3c[c] = w3[col]; b2c[c] = b2[col];
    }
    #pragma unroll 1
    for (int t = 0; t < 4; ++t) {
        int base = rowbase + t*16;
        int arow = base + (l & 15); if (arow >= NN) arow = NN - 1;
        s8v af[4];
        #pragma unroll
        for (int s = 0; s < 4; ++s)
            af[s] = *(const s8v*)(h4b + (size_t)arow*128 + s*32 + koff);
        float zp0 = 0.f, zp1 = 0.f, zp2 = 0.f, zp3 = 0.f;
        #pragma unroll
        for (int c = 0; c < 4; ++c) {
            const s8v* bf = (c == 0) ? bf0 : (c == 1) ? bf1 : (c == 2) ? bf2 : bf3;
            f4v accA = {0.f,0.f,0.f,0.f}, accB = {0.f,0.f,0.f,0.f};
            accA = __builtin_amdgcn_mfma_f32_16x16x32_bf16(af[0], bf[0], accA, 0, 0, 0);
            accA = __builtin_amdgcn_mfma_f32_16x16x32_bf16(af[1], bf[1], accA, 0, 0, 0);
            accB = __builtin_amdgcn_mfma_f32_16x16x32_bf16(af[2], bf[2], accB, 0, 0, 0);
            accB = __builtin_amdgcn_mfma_f32_16x16x32_bf16(af[3], bf[3], accB, 0, 0, 0);
            zp0 += fmaxf(accA[0]+accB[0] + b2c[c], 0.f) * w3c[c];
            zp1 += fmaxf(accA[1]+accB[1] + b2c[c], 0.f) * w3c[c];
            zp2 += fmaxf(accA[2]+accB[2] + b2c[c], 0.f) * w3c[c];
            zp3 += fmaxf(accA[3]+accB[3] + b2c[c], 0.f) * w3c[c];
        }
        #pragma unroll
        for (int m = 1; m < 16; m <<= 1) {
            zp0 += __shfl_xor(zp0, m, 64);
            zp1 += __shfl_xor(zp1, m, 64);
            zp2 += __shfl_xor(zp2, m, 64);
            zp3 += __shfl_xor(zp3, m, 64);
        }
        if ((l & 15) == 0) {
            int r0 = base + (l >> 4) * 4;
            if (r0+0 < NN) atomicAdd(&z[r0+0], zp0);
            if (r0+1 < NN) atomicAdd(&z[r0+1], zp1);
            if (r0+2 < NN) atomicAdd(&z[r0+2], zp2);
            if (r0+3 < NN) atomicAdd(&z[r0+3], zp3);
        }
    }
}

__global__ void sigmoid_kernel(const float* __restrict__ z,
                               const float* __restrict__ b3,
                               float* __restrict__ p) {
    int n = blockIdx.x * 256 + threadIdx.x;
    if (n < NN) p[n] = 1.f / (1.f + expf(-(z[n] + b3[0])));
}

// ---------------- loss ----------------
__global__ void loss_pass_kernel(const float* __restrict__ labels,
                                 const float* __restrict__ p,
                                 float* __restrict__ scal) {
    __shared__ float sh0[256], sh1[256], sh2[256];
    int tid = threadIdx.x;
    float pos = 0.f, sp = 0.f, sn = 0.f;
    for (int n = blockIdx.x*256 + tid; n < NN; n += gridDim.x*256) {
        float yv = labels[n], pv = p[n];
        if (yv == 1.0f) { pos += 1.f; sp -= fmaxf(logf(pv), -100.f); }
        else            { sn -= fmaxf(logf(1.f - pv), -100.f); }
    }
    sh0[tid] = pos; sh1[tid] = sp; sh2[tid] = sn;
    __syncthreads();
    for (int off = 128; off; off >>= 1) {
        if (tid < off) {
            sh0[tid] += sh0[tid+off];
            sh1[tid] += sh1[tid+off];
            sh2[tid] += sh2[tid+off];
        }
        __syncthreads();
    }
    if (tid == 0) {
        atomicAdd(&scal[0], sh0[0]);
        atomicAdd(&scal[1], sh1[0]);
        atomicAdd(&scal[2], sh2[0]);
    }
}

__global__ void loss_final_kernel(const float* __restrict__ scal,
                                  float* __restrict__ out) {
    float pos = scal[0];
    out[0] = scal[1] / (2.f*pos) + scal[2] / (2.f*((float)NN - pos));
}

// ---------------- launch ----------------
extern "C" void kernel_launch(void* const* d_in, const int* in_sizes, int n_in,
                              void* d_out, int out_size, void* d_ws, size_t ws_size,
                              hipStream_t stream) {
    (void)in_sizes; (void)n_in; (void)out_size; (void)ws_size;
    const float* x   = (const float*)d_in[0];
    const int*   ei  = (const int*)d_in[1];
    const float* labels = (const float*)d_in[2];
    const float* l1w = (const float*)d_in[3];
    const float* l1b = (const float*)d_in[4];
    const float* cw[3] = {(const float*)d_in[5], (const float*)d_in[9],  (const float*)d_in[13]};
    const float* cu[3] = {(const float*)d_in[6], (const float*)d_in[10], (const float*)d_in[14]};
    const float* cc[3] = {(const float*)d_in[7], (const float*)d_in[11], (const float*)d_in[15]};
    const float* cb[3] = {(const float*)d_in[8], (const float*)d_in[12], (const float*)d_in[16]};
    const float* l2w = (const float*)d_in[17];
    const float* l2b = (const float*)d_in[18];
    const float* l3w = (const float*)d_in[19];
    const float* l3b = (const float*)d_in[20];
    const int* srcp = ei;
    const int* dstp = ei + NE;
    float* out = (float*)d_out;

    // ---- workspace (float units, 64B aligned) ----
    float* ws = (float*)d_ws;
    size_t off = 0;
    auto alloc = [&](size_t n) { float* p = ws + off; off += (n + 15) & ~(size_t)15; return p; };
    float* hA = alloc((size_t)NN*64);                 // h1(N,16) then h3(N,64)
    float* hB = alloc((size_t)NN*128);                // h2(N,32) then h4 (bf16)
    float* a  = alloc((size_t)NN*8);
    unsigned short* g   = (unsigned short*)alloc((size_t)NN*256);  // N x 512 bf16 max
    unsigned short* w2p = (unsigned short*)alloc(65536);
    unsigned short* wf1 = (unsigned short*)alloc(2048);
    unsigned short* wf2 = (unsigned short*)alloc(8192);
    unsigned short* wf3 = (unsigned short*)alloc(32768);
    float* z    = alloc(NN);
    float* scal = alloc(16);
    int* rowptr = (int*)alloc(50016);
    int* fill   = (int*)alloc(NN);
    int* fill2  = (int*)alloc(NN);
    int* ssrc   = (int*)alloc(NE);
    int* sdst   = (int*)alloc(NE);
    int* bpart  = (int*)alloc(256);
    float* qs1 = hB;      // conv1 out = hB (f32)
    float* qs2 = hA;      // conv2 out = hA (f32)
    float* qs3 = hB;      // conv3 out = hB (bf16, written after qs3 consumed)
    unsigned short* h4b = (unsigned short*)hB;

    const int SCAN_BLKS = (NN + 255) / 256;           // 196
    const int GB = (NN + 63) / 64;                    // 782
    const int PREP_BLKS = 106 + (3*NN + 16 + 255) / 256;

    // ---- prep (packs + zeroing) + CSR build ----
    prep_kernel<<<PREP_BLKS, 256, 0, stream>>>(l2w, w2p, cw[0], wf1, cw[1], wf2,
                                               cw[2], wf3, fill, fill2, z, scal);
    hist_kernel<<<(NE+255)/256, 256, 0, stream>>>(dstp, fill);
    scan1_kernel<<<SCAN_BLKS, 256, 0, stream>>>(fill, rowptr, bpart);
    scan2_kernel<<<1, 256, 0, stream>>>(bpart, SCAN_BLKS);
    scan3_kernel<<<SCAN_BLKS, 256, 0, stream>>>(rowptr, bpart);
    scatter_kernel<<<(NE+255)/256, 256, 0, stream>>>(srcp, dstp, rowptr, fill2, ssrc, sdst);

    // ---- lin1 ----
    lin1_kernel<<<(NN*16+255)/256, 256, 0, stream>>>(x, l1w, l1b, hA);

    // ---- conv1: cin=16 -> O=32 (hA -> hB f32) ----
    a_kernel<16><<<(NN*8+255)/256, 256, 0, stream>>>(hA, cu[0], a);
    q_sorted_kernel<<<(NE+255)/256, 256, 0, stream>>>(ssrc, sdst, a, cc[0], qs1);
    agg_kernel<16><<<NN/4, 256, 0, stream>>>(hA, cc[0], rowptr, ssrc, qs1, g);
    gemm_feast<128,32,2,false><<<GB, 256, 0, stream>>>(g, wf1, rowptr, cb[0], hB, nullptr);

    // ---- conv2: cin=32 -> O=64 (hB -> hA f32) ----
    a_kernel<32><<<(NN*8+255)/256, 256, 0, stream>>>(hB, cu[1], a);
    q_sorted_kernel<<<(NE+255)/256, 256, 0, stream>>>(ssrc, sdst, a, cc[1], qs2);
    agg_kernel<32><<<NN/4, 256, 0, stream>>>(hB, cc[1], rowptr, ssrc, qs2, g);
    gemm_feast<256,64,4,false><<<GB, 256, 0, stream>>>(g, wf2, rowptr, cb[1], hA, nullptr);

    // ---- conv3: cin=64 -> O=128 (hA -> hB bf16 direct) ----
    a_kernel<64><<<(NN*8+255)/256, 256, 0, stream>>>(hA, cu[2], a);
    q_sorted_kernel<<<(NE+255)/256, 256, 0, stream>>>(ssrc, sdst, a, cc[2], qs3);
    agg_kernel<64><<<NN/4, 256, 0, stream>>>(hA, cc[2], rowptr, ssrc, qs3, g);
    gemm_feast<512,128,2,true><<<GB, 256, 0, stream>>>(g, wf3, rowptr, cb[2], nullptr, h4b);

    // ---- lin2+lin3: split-ct z reduction, then sigmoid ----
    lin23z_kernel<<<dim3((NN+255)/256, 16), 256, 0, stream>>>(h4b, w2p, l2b, l3w, z);
    sigmoid_kernel<<<SCAN_BLKS, 256, 0, stream>>>(z, l3b, out + 1);

    // ---- loss ----
    loss_pass_kernel<<<256, 256, 0, stream>>>(labels, out + 1, scal);
    loss_final_kernel<<<1, 1, 0, stream>>>(scal, out);
}

// Round 9
// 259.366 us; speedup vs baseline: 21.2089x; 1.0456x over previous
//
#include <hip/hip_runtime.h>
#include <math.h>

#define NN 50000
#define NE 300000

typedef short s8v __attribute__((ext_vector_type(8)));
typedef float f4v __attribute__((ext_vector_type(4)));

__device__ inline unsigned short f2bf(float f) {
    union { float f; unsigned int u; } v; v.f = f;
    unsigned int r = v.u + 0x7FFFu + ((v.u >> 16) & 1u);
    return (unsigned short)(r >> 16);
}

// ---------------- weight pack bodies ----------------
template<int CIN, int O>
__device__ inline void packw_feast_body(const float* __restrict__ W,
                                        unsigned short* __restrict__ wp, int t) {
    constexpr int NS = (8*CIN) / 32;
    int l = t & 63;
    int s = (t >> 6) % NS;
    int ct = t / (64 * NS);
    int c = ct*16 + (l & 15);
    int kk0 = s*32 + (l >> 4) * 8;
    union { unsigned short u[8]; s8v v; } o;
    #pragma unroll
    for (int i = 0; i < 8; ++i) {
        int kk = kk0 + i;
        int h = kk / CIN, k = kk & (CIN - 1);
        o.u[i] = f2bf(W[(size_t)k*(8*O) + h*O + c]);
    }
    *(s8v*)(wp + (size_t)t*8) = o.v;
}

__device__ inline void packw_lin_body(const float* __restrict__ W,
                                      unsigned short* __restrict__ wp, int t) {
    int l = t & 63;
    int s = (t >> 6) & 3;
    int ctg = t >> 8;
    int c = ctg*16 + (l & 15);
    int k0 = s*32 + (l >> 4) * 8;
    union { unsigned short u[8]; s8v v; } o;
    #pragma unroll
    for (int i = 0; i < 8; ++i) o.u[i] = f2bf(W[(size_t)(k0+i)*1024 + c]);
    *(s8v*)(wp + (size_t)t*8) = o.v;
}

// ---------------- mega-prep: packs + zeroing + lin1 + a1, one dispatch -----
// blocks [0,106): weight packs; [106,693): zero fill/fill2/z/scal;
// [693,3818): lin1 (16 nodes/block) + a1 = h1 @ u1 via LDS tile.
__global__ __launch_bounds__(256) void prep_kernel(
        const float* __restrict__ l2w, unsigned short* __restrict__ w2p,
        const float* __restrict__ wf1w, unsigned short* __restrict__ wf1,
        const float* __restrict__ wf2w, unsigned short* __restrict__ wf2,
        const float* __restrict__ wf3w, unsigned short* __restrict__ wf3,
        int* __restrict__ fill, int* __restrict__ fill2,
        float* __restrict__ z, float* __restrict__ scal,
        const float* __restrict__ x, const float* __restrict__ l1w,
        const float* __restrict__ l1b, const float* __restrict__ u1,
        float* __restrict__ h1, float* __restrict__ a) {
    __shared__ float hsh[16][16];
    int b = blockIdx.x;
    int tid = threadIdx.x;
    if (b < 64)  { packw_lin_body(l2w, w2p, b*256 + tid); return; }
    b -= 64;
    if (b < 2)   { packw_feast_body<16,32>(wf1w, wf1, b*256 + tid); return; }
    b -= 2;
    if (b < 8)   { packw_feast_body<32,64>(wf2w, wf2, b*256 + tid); return; }
    b -= 8;
    if (b < 32)  { packw_feast_body<64,128>(wf3w, wf3, b*256 + tid); return; }
    b -= 32;
    if (b < 587) {
        int idx = b*256 + tid;
        if (idx < NN)            fill[idx] = 0;
        else if (idx < 2*NN)     fill2[idx - NN] = 0;
        else if (idx < 3*NN)     z[idx - 2*NN] = 0.f;
        else if (idx < 3*NN+16)  scal[idx - 3*NN] = 0.f;
        return;
    }
    b -= 587;                        // 0..3124 : lin1 + a1
    int n0 = b * 16;
    int node = n0 + (tid >> 4), col = tid & 15;
    float v = x[node*3+0]*l1w[col] + x[node*3+1]*l1w[16+col]
            + x[node*3+2]*l1w[32+col] + l1b[col];
    v = fmaxf(v, 0.f);
    h1[(size_t)node*16 + col] = v;
    hsh[tid >> 4][col] = v;
    __syncthreads();
    if (tid < 128) {
        int t2 = tid >> 3, h = tid & 7;
        float acc = 0.f;
        #pragma unroll
        for (int k = 0; k < 16; ++k) acc += hsh[t2][k] * u1[k*8 + h];
        a[(size_t)(n0 + t2)*8 + h] = acc;
    }
}

// ---------------- CSR build ----------------
__global__ void hist_kernel(const int* __restrict__ dst, int* __restrict__ cnt) {
    int e = blockIdx.x * 256 + threadIdx.x;
    if (e < NE) atomicAdd(&cnt[dst[e]], 1);
}

__global__ void scan1_kernel(const int* __restrict__ cnt, int* __restrict__ rp,
                             int* __restrict__ bpart) {
    __shared__ int sh[256];
    int tid = threadIdx.x;
    int gid = blockIdx.x * 256 + tid;
    int v = (gid < NN) ? cnt[gid] : 0;
    sh[tid] = v;
    __syncthreads();
    for (int off = 1; off < 256; off <<= 1) {
        int t = (tid >= off) ? sh[tid - off] : 0;
        __syncthreads();
        sh[tid] += t;
        __syncthreads();
    }
    if (gid < NN) rp[gid] = sh[tid] - v;            // exclusive within block
    if (tid == 255) bpart[blockIdx.x] = sh[tid];    // block total
}

// scan3 with inline reduction of bpart[0..blockIdx) (replaces scan2+scan3)
__global__ void scanfix_kernel(int* __restrict__ rp, const int* __restrict__ bpart,
                               int nblk) {
    __shared__ int sh[256];
    int tid = threadIdx.x;
    int bx = blockIdx.x;
    sh[tid] = (tid < bx && tid < nblk) ? bpart[tid] : 0;
    __syncthreads();
    for (int off = 128; off; off >>= 1) {
        if (tid < off) sh[tid] += sh[tid + off];
        __syncthreads();
    }
    int add = sh[0];
    int gid = bx * 256 + tid;
    if (gid < NN) rp[gid] += add;
    if (gid == 0) rp[NN] = NE;
}

__global__ void scatter_kernel(const int* __restrict__ src, const int* __restrict__ dst,
                               const int* __restrict__ rp, int* __restrict__ fill,
                               int* __restrict__ ssrc, int* __restrict__ sdst) {
    int e = blockIdx.x * 256 + threadIdx.x;
    if (e >= NE) return;
    int d = dst[e];
    int pos = rp[d] + atomicAdd(&fill[d], 1);
    ssrc[pos] = src[e];
    sdst[pos] = d;
}

// ---------------- q over sorted edges ----------------
__global__ void q_sorted_kernel(const int* __restrict__ ssrc,
                                const int* __restrict__ sdst,
                                const float* __restrict__ a,
                                const float* __restrict__ c,
                                float* __restrict__ qs) {
    int j = blockIdx.x * 256 + threadIdx.x;
    if (j >= NE) return;
    int s = ssrc[j], d = sdst[j];
    const float4* as = (const float4*)(a + (size_t)s*8);
    const float4* ad = (const float4*)(a + (size_t)d*8);
    float4 s0 = as[0], s1 = as[1], d0 = ad[0], d1 = ad[1];
    float lg[8] = { s0.x-d0.x+c[0], s0.y-d0.y+c[1], s0.z-d0.z+c[2], s0.w-d0.w+c[3],
                    s1.x-d1.x+c[4], s1.y-d1.y+c[5], s1.z-d1.z+c[6], s1.w-d1.w+c[7] };
    float m = lg[0];
    #pragma unroll
    for (int h = 1; h < 8; ++h) m = fmaxf(m, lg[h]);
    float sum = 0.f;
    #pragma unroll
    for (int h = 0; h < 8; ++h) { lg[h] = __expf(lg[h]-m); sum += lg[h]; }
    float inv = 1.f / sum;
    float4* qp = (float4*)(qs + (size_t)j*8);
    qp[0] = make_float4(lg[0]*inv, lg[1]*inv, lg[2]*inv, lg[3]*inv);
    qp[1] = make_float4(lg[4]*inv, lg[5]*inv, lg[6]*inv, lg[7]*inv);
}

// ---------------- agg ----------------
template<int HPER>
__device__ inline void load_qv(const float* __restrict__ qs, int j, int hg, float* qv) {
    if constexpr (HPER == 2) {
        float2 t = *(const float2*)(qs + (size_t)j*8 + hg*2);
        qv[0] = t.x; qv[1] = t.y;
    } else if constexpr (HPER == 4) {
        float4 t = *(const float4*)(qs + (size_t)j*8 + hg*4);
        qv[0] = t.x; qv[1] = t.y; qv[2] = t.z; qv[3] = t.w;
    } else {
        float4 t0 = *(const float4*)(qs + (size_t)j*8);
        float4 t1 = *(const float4*)(qs + (size_t)j*8 + 4);
        qv[0] = t0.x; qv[1] = t0.y; qv[2] = t0.z; qv[3] = t0.w;
        qv[4] = t1.x; qv[5] = t1.y; qv[6] = t1.z; qv[7] = t1.w;
    }
}

template<int CIN>
__global__ __launch_bounds__(256) void agg_kernel(
        const float* __restrict__ hin, const float* __restrict__ cbias,
        const int* __restrict__ rowptr, const int* __restrict__ ssrc,
        const float* __restrict__ qs, unsigned short* __restrict__ g) {
    constexpr int HPER = CIN / 8;
    constexpr int LG = (CIN == 16) ? 4 : (CIN == 32) ? 5 : 6;
    const int lane = threadIdx.x & 63;
    const int d = blockIdx.x * 4 + (threadIdx.x >> 6);
    const int k = lane & (CIN - 1);
    const int hg = lane >> LG;
    float m = cbias[0];
    #pragma unroll
    for (int h = 1; h < 8; ++h) m = fmaxf(m, cbias[h]);
    float ssum = 0.f;
    #pragma unroll
    for (int h = 0; h < 8; ++h) ssum += __expf(cbias[h] - m);
    float sinv = 1.f / ssum;
    float xd = hin[(size_t)d*CIN + k];
    float acc[HPER];
    #pragma unroll
    for (int i = 0; i < HPER; ++i)
        acc[i] = __expf(cbias[hg*HPER + i] - m) * sinv * xd;
    int j0 = rowptr[d], j1 = rowptr[d+1];
    int j = j0;
    for (; j + 2 <= j1; j += 2) {
        int s0 = ssrc[j], s1 = ssrc[j+1];
        float xv0 = hin[(size_t)s0*CIN + k];
        float xv1 = hin[(size_t)s1*CIN + k];
        float qv0[HPER], qv1[HPER];
        load_qv<HPER>(qs, j, hg, qv0);
        load_qv<HPER>(qs, j+1, hg, qv1);
        #pragma unroll
        for (int i = 0; i < HPER; ++i) acc[i] += qv0[i]*xv0 + qv1[i]*xv1;
    }
    if (j < j1) {
        int s0 = ssrc[j];
        float xv0 = hin[(size_t)s0*CIN + k];
        float qv0[HPER];
        load_qv<HPER>(qs, j, hg, qv0);
        #pragma unroll
        for (int i = 0; i < HPER; ++i) acc[i] += qv0[i]*xv0;
    }
    #pragma unroll
    for (int i = 0; i < HPER; ++i)
        g[(size_t)d*(8*CIN) + (hg*HPER + i)*CIN + k] = f2bf(acc[i]);
}

// ---------------- feast GEMM (+ optional a-epilogue for next layer) --------
template<int K, int O, int CH, bool BF16OUT, bool AEPI>
__global__ __launch_bounds__(256) void gemm_feast(
        const unsigned short* __restrict__ g, const unsigned short* __restrict__ wp,
        const int* __restrict__ rowptr, const float* __restrict__ b,
        float* __restrict__ houtf, unsigned short* __restrict__ houtb,
        const float* __restrict__ unext, float* __restrict__ aout) {
    constexpr int NS = K / 32;
    constexpr int NCT = O / 16;
    __shared__ unsigned short bsh[CH*NS*64*8];
    const int l = threadIdx.x & 63;
    const int w = threadIdx.x >> 6;
    const int base = blockIdx.x * 64 + w * 16;
    int arow = base + (l & 15); if (arow >= NN) arow = NN - 1;
    const int koff = (l >> 4) * 8;
    s8v af[NS];
    #pragma unroll
    for (int s = 0; s < NS; ++s)
        af[s] = *(const s8v*)(g + (size_t)arow*K + s*32 + koff);
    float invc[4];
    #pragma unroll
    for (int r = 0; r < 4; ++r) {
        int n = base + (l >> 4)*4 + r; if (n >= NN) n = NN - 1;
        invc[r] = 1.f / (float)(rowptr[n+1] - rowptr[n] + 1);
    }
    float apart[4][8];
    if constexpr (AEPI) {
        #pragma unroll
        for (int r = 0; r < 4; ++r)
            #pragma unroll
            for (int h = 0; h < 8; ++h) apart[r][h] = 0.f;
    }
    #pragma unroll 1
    for (int ct0 = 0; ct0 < NCT; ct0 += CH) {
        __syncthreads();
        const int4* sp = (const int4*)(wp + (size_t)ct0*NS*512);
        int4* dp = (int4*)bsh;
        #pragma unroll 1
        for (int i = threadIdx.x; i < CH*NS*64; i += 256) dp[i] = sp[i];
        __syncthreads();
        #pragma unroll 1
        for (int cc = 0; cc < CH; ++cc) {
            f4v accA = {0.f,0.f,0.f,0.f}, accB = {0.f,0.f,0.f,0.f};
            #pragma unroll
            for (int s = 0; s < NS/2; ++s) {
                s8v bf = *(const s8v*)(bsh + ((size_t)(cc*NS + s)*64 + l)*8);
                accA = __builtin_amdgcn_mfma_f32_16x16x32_bf16(af[s], bf, accA, 0, 0, 0);
            }
            #pragma unroll
            for (int s = NS/2; s < NS; ++s) {
                s8v bf = *(const s8v*)(bsh + ((size_t)(cc*NS + s)*64 + l)*8);
                accB = __builtin_amdgcn_mfma_f32_16x16x32_bf16(af[s], bf, accB, 0, 0, 0);
            }
            int col = (ct0 + cc)*16 + (l & 15);
            float bb = b[col];
            float uv[8];
            if constexpr (AEPI) {
                #pragma unroll
                for (int h = 0; h < 8; ++h) uv[h] = unext[col*8 + h];
            }
            #pragma unroll
            for (int r = 0; r < 4; ++r) {
                int n = base + (l >> 4)*4 + r;
                float v = fmaxf((accA[r]+accB[r])*invc[r] + bb, 0.f);
                if constexpr (AEPI) {
                    #pragma unroll
                    for (int h = 0; h < 8; ++h) apart[r][h] += v * uv[h];
                }
                if (n < NN) {
                    if constexpr (BF16OUT) houtb[(size_t)n*O + col] = f2bf(v);
                    else                   houtf[(size_t)n*O + col] = v;
                }
            }
        }
    }
    if constexpr (AEPI) {
        #pragma unroll
        for (int r = 0; r < 4; ++r)
            #pragma unroll
            for (int h = 0; h < 8; ++h) {
                float v = apart[r][h];
                v += __shfl_xor(v, 1, 64);
                v += __shfl_xor(v, 2, 64);
                v += __shfl_xor(v, 4, 64);
                v += __shfl_xor(v, 8, 64);
                if ((l & 15) == 0) {
                    int n = base + (l >> 4)*4 + r;
                    if (n < NN) aout[(size_t)n*8 + h] = v;
                }
            }
    }
}

// ---------------- lin23 split-ct z reduction ----------------
__global__ __launch_bounds__(256) void lin23z_kernel(
        const unsigned short* __restrict__ h4b, const unsigned short* __restrict__ w2p,
        const float* __restrict__ b2, const float* __restrict__ w3,
        float* __restrict__ z) {
    const int l = threadIdx.x & 63;
    const int w = threadIdx.x >> 6;
    const int ctg = blockIdx.y;                       // 0..15 -> 4 ct each
    const int rowbase = blockIdx.x * 256 + w * 64;
    const int koff = (l >> 4) * 8;
    s8v bf0[4], bf1[4], bf2[4], bf3[4];
    #pragma unroll
    for (int s = 0; s < 4; ++s) {
        bf0[s] = *(const s8v*)(w2p + ((size_t)((ctg*4+0)*4 + s)*64 + l)*8);
        bf1[s] = *(const s8v*)(w2p + ((size_t)((ctg*4+1)*4 + s)*64 + l)*8);
        bf2[s] = *(const s8v*)(w2p + ((size_t)((ctg*4+2)*4 + s)*64 + l)*8);
        bf3[s] = *(const s8v*)(w2p + ((size_t)((ctg*4+3)*4 + s)*64 + l)*8);
    }
    float w3c[4], b2c[4];
    #pragma unroll
    for (int c = 0; c < 4; ++c) {
        int col = (ctg*4 + c)*16 + (l & 15);
        w3c[c] = w3[col]; b2c[c] = b2[col];
    }
    #pragma unroll 1
    for (int t = 0; t < 4; ++t) {
        int base = rowbase + t*16;
        int arow = base + (l & 15); if (arow >= NN) arow = NN - 1;
        s8v af[4];
        #pragma unroll
        for (int s = 0; s < 4; ++s)
            af[s] = *(const s8v*)(h4b + (size_t)arow*128 + s*32 + koff);
        float zp0 = 0.f, zp1 = 0.f, zp2 = 0.f, zp3 = 0.f;
        #pragma unroll
        for (int c = 0; c < 4; ++c) {
            const s8v* bf = (c == 0) ? bf0 : (c == 1) ? bf1 : (c == 2) ? bf2 : bf3;
            f4v accA = {0.f,0.f,0.f,0.f}, accB = {0.f,0.f,0.f,0.f};
            accA = __builtin_amdgcn_mfma_f32_16x16x32_bf16(af[0], bf[0], accA, 0, 0, 0);
            accA = __builtin_amdgcn_mfma_f32_16x16x32_bf16(af[1], bf[1], accA, 0, 0, 0);
            accB = __builtin_amdgcn_mfma_f32_16x16x32_bf16(af[2], bf[2], accB, 0, 0, 0);
            accB = __builtin_amdgcn_mfma_f32_16x16x32_bf16(af[3], bf[3], accB, 0, 0, 0);
            zp0 += fmaxf(accA[0]+accB[0] + b2c[c], 0.f) * w3c[c];
            zp1 += fmaxf(accA[1]+accB[1] + b2c[c], 0.f) * w3c[c];
            zp2 += fmaxf(accA[2]+accB[2] + b2c[c], 0.f) * w3c[c];
            zp3 += fmaxf(accA[3]+accB[3] + b2c[c], 0.f) * w3c[c];
        }
        #pragma unroll
        for (int m = 1; m < 16; m <<= 1) {
            zp0 += __shfl_xor(zp0, m, 64);
            zp1 += __shfl_xor(zp1, m, 64);
            zp2 += __shfl_xor(zp2, m, 64);
            zp3 += __shfl_xor(zp3, m, 64);
        }
        if ((l & 15) == 0) {
            int r0 = base + (l >> 4) * 4;
            if (r0+0 < NN) atomicAdd(&z[r0+0], zp0);
            if (r0+1 < NN) atomicAdd(&z[r0+1], zp1);
            if (r0+2 < NN) atomicAdd(&z[r0+2], zp2);
            if (r0+3 < NN) atomicAdd(&z[r0+3], zp3);
        }
    }
}

// ---------------- finish: sigmoid + balanced-BCE loss, last-block finalize -
__global__ void finish_kernel(const float* __restrict__ labels,
                              const float* __restrict__ z,
                              const float* __restrict__ b3,
                              float* __restrict__ p,
                              float* __restrict__ scal,
                              float* __restrict__ out, int nblk) {
    __shared__ float sh0[256], sh1[256], sh2[256];
    int tid = threadIdx.x;
    int n = blockIdx.x * 256 + tid;
    float pos = 0.f, sp = 0.f, sn = 0.f;
    if (n < NN) {
        float pv = 1.f / (1.f + expf(-(z[n] + b3[0])));
        p[n] = pv;
        float yv = labels[n];
        if (yv == 1.0f) { pos = 1.f; sp = -fmaxf(logf(pv), -100.f); }
        else            { sn = -fmaxf(logf(1.f - pv), -100.f); }
    }
    sh0[tid] = pos; sh1[tid] = sp; sh2[tid] = sn;
    __syncthreads();
    for (int off = 128; off; off >>= 1) {
        if (tid < off) {
            sh0[tid] += sh0[tid+off];
            sh1[tid] += sh1[tid+off];
            sh2[tid] += sh2[tid+off];
        }
        __syncthreads();
    }
    if (tid == 0) {
        atomicAdd(&scal[0], sh0[0]);
        atomicAdd(&scal[1], sh1[0]);
        atomicAdd(&scal[2], sh2[0]);
        __threadfence();
        int t = atomicAdd((int*)&scal[4], 1);
        if (t == nblk - 1) {
            float posT = atomicAdd(&scal[0], 0.f);
            float spT  = atomicAdd(&scal[1], 0.f);
            float snT  = atomicAdd(&scal[2], 0.f);
            out[0] = spT / (2.f*posT) + snT / (2.f*((float)NN - posT));
        }
    }
}

// ---------------- launch ----------------
extern "C" void kernel_launch(void* const* d_in, const int* in_sizes, int n_in,
                              void* d_out, int out_size, void* d_ws, size_t ws_size,
                              hipStream_t stream) {
    (void)in_sizes; (void)n_in; (void)out_size; (void)ws_size;
    const float* x   = (const float*)d_in[0];
    const int*   ei  = (const int*)d_in[1];
    const float* labels = (const float*)d_in[2];
    const float* l1w = (const float*)d_in[3];
    const float* l1b = (const float*)d_in[4];
    const float* cw[3] = {(const float*)d_in[5], (const float*)d_in[9],  (const float*)d_in[13]};
    const float* cu[3] = {(const float*)d_in[6], (const float*)d_in[10], (const float*)d_in[14]};
    const float* cc[3] = {(const float*)d_in[7], (const float*)d_in[11], (const float*)d_in[15]};
    const float* cb[3] = {(const float*)d_in[8], (const float*)d_in[12], (const float*)d_in[16]};
    const float* l2w = (const float*)d_in[17];
    const float* l2b = (const float*)d_in[18];
    const float* l3w = (const float*)d_in[19];
    const float* l3b = (const float*)d_in[20];
    const int* srcp = ei;
    const int* dstp = ei + NE;
    float* out = (float*)d_out;

    // ---- workspace (float units, 64B aligned) ----
    float* ws = (float*)d_ws;
    size_t off = 0;
    auto alloc = [&](size_t n) { float* p = ws + off; off += (n + 15) & ~(size_t)15; return p; };
    float* hA = alloc((size_t)NN*64);                 // h1(N,16) then h3(N,64)
    float* hB = alloc((size_t)NN*128);                // h2(N,32) then h4 (bf16)
    float* a  = alloc((size_t)NN*8);
    unsigned short* g   = (unsigned short*)alloc((size_t)NN*256);
    unsigned short* w2p = (unsigned short*)alloc(65536);
    unsigned short* wf1 = (unsigned short*)alloc(2048);
    unsigned short* wf2 = (unsigned short*)alloc(8192);
    unsigned short* wf3 = (unsigned short*)alloc(32768);
    float* z    = alloc(NN);
    float* scal = alloc(16);
    int* rowptr = (int*)alloc(50016);
    int* fill   = (int*)alloc(NN);
    int* fill2  = (int*)alloc(NN);
    int* ssrc   = (int*)alloc(NE);
    int* sdst   = (int*)alloc(NE);
    int* bpart  = (int*)alloc(256);
    float* qs1 = hB;      // conv1 out = hB (f32)
    float* qs2 = hA;      // conv2 out = hA (f32)
    float* qs3 = hB;      // conv3 out = hB (bf16, written after qs3 consumed)
    unsigned short* h4b = (unsigned short*)hB;

    const int SCAN_BLKS = (NN + 255) / 256;           // 196
    const int GB = (NN + 63) / 64;                    // 782
    const int PREP_BLKS = 106 + 587 + NN/16;          // 3818

    // ---- prep (packs + zeroing + lin1 + a1) + CSR build ----
    prep_kernel<<<PREP_BLKS, 256, 0, stream>>>(l2w, w2p, cw[0], wf1, cw[1], wf2,
                                               cw[2], wf3, fill, fill2, z, scal,
                                               x, l1w, l1b, cu[0], hA, a);
    hist_kernel<<<(NE+255)/256, 256, 0, stream>>>(dstp, fill);
    scan1_kernel<<<SCAN_BLKS, 256, 0, stream>>>(fill, rowptr, bpart);
    scanfix_kernel<<<SCAN_BLKS, 256, 0, stream>>>(rowptr, bpart, SCAN_BLKS);
    scatter_kernel<<<(NE+255)/256, 256, 0, stream>>>(srcp, dstp, rowptr, fill2, ssrc, sdst);

    // ---- conv1: cin=16 -> O=32 (hA -> hB f32); epilogue a2 = h2@u2 ----
    q_sorted_kernel<<<(NE+255)/256, 256, 0, stream>>>(ssrc, sdst, a, cc[0], qs1);
    agg_kernel<16><<<NN/4, 256, 0, stream>>>(hA, cc[0], rowptr, ssrc, qs1, g);
    gemm_feast<128,32,2,false,true><<<GB, 256, 0, stream>>>(g, wf1, rowptr, cb[0], hB, nullptr, cu[1], a);

    // ---- conv2: cin=32 -> O=64 (hB -> hA f32); epilogue a3 = h3@u3 ----
    q_sorted_kernel<<<(NE+255)/256, 256, 0, stream>>>(ssrc, sdst, a, cc[1], qs2);
    agg_kernel<32><<<NN/4, 256, 0, stream>>>(hB, cc[1], rowptr, ssrc, qs2, g);
    gemm_feast<256,64,4,false,true><<<GB, 256, 0, stream>>>(g, wf2, rowptr, cb[1], hA, nullptr, cu[2], a);

    // ---- conv3: cin=64 -> O=128 (hA -> hB bf16 direct) ----
    q_sorted_kernel<<<(NE+255)/256, 256, 0, stream>>>(ssrc, sdst, a, cc[2], qs3);
    agg_kernel<64><<<NN/4, 256, 0, stream>>>(hA, cc[2], rowptr, ssrc, qs3, g);
    gemm_feast<512,128,2,true,false><<<GB, 256, 0, stream>>>(g, wf3, rowptr, cb[2], nullptr, h4b, nullptr, nullptr);

    // ---- lin2+lin3 z reduction, then sigmoid+loss (fused) ----
    lin23z_kernel<<<dim3((NN+255)/256, 16), 256, 0, stream>>>(h4b, w2p, l2b, l3w, z);
    finish_kernel<<<SCAN_BLKS, 256, 0, stream>>>(labels, z, l3b, out + 1, scal, out, SCAN_BLKS);
}

// Round 10
// 246.278 us; speedup vs baseline: 22.3360x; 1.0531x over previous
//
#include <hip/hip_runtime.h>
#include <math.h>

#define NN 50000
#define NE 300000

typedef short s8v __attribute__((ext_vector_type(8)));
typedef float f4v __attribute__((ext_vector_type(4)));

__device__ inline unsigned short f2bf(float f) {
    union { float f; unsigned int u; } v; v.f = f;
    unsigned int r = v.u + 0x7FFFu + ((v.u >> 16) & 1u);
    return (unsigned short)(r >> 16);
}
__device__ inline float bf2f(unsigned short u) {
    union { unsigned int i; float f; } v; v.i = ((unsigned int)u) << 16;
    return v.f;
}

// ---------------- weight pack bodies ----------------
template<int CIN, int O>
__device__ inline void packw_feast_body(const float* __restrict__ W,
                                        unsigned short* __restrict__ wp, int t) {
    constexpr int NS = (8*CIN) / 32;
    int l = t & 63;
    int s = (t >> 6) % NS;
    int ct = t / (64 * NS);
    int c = ct*16 + (l & 15);
    int kk0 = s*32 + (l >> 4) * 8;
    union { unsigned short u[8]; s8v v; } o;
    #pragma unroll
    for (int i = 0; i < 8; ++i) {
        int kk = kk0 + i;
        int h = kk / CIN, k = kk & (CIN - 1);
        o.u[i] = f2bf(W[(size_t)k*(8*O) + h*O + c]);
    }
    *(s8v*)(wp + (size_t)t*8) = o.v;
}

__device__ inline void packw_lin_body(const float* __restrict__ W,
                                      unsigned short* __restrict__ wp, int t) {
    int l = t & 63;
    int s = (t >> 6) & 3;
    int ctg = t >> 8;
    int c = ctg*16 + (l & 15);
    int k0 = s*32 + (l >> 4) * 8;
    union { unsigned short u[8]; s8v v; } o;
    #pragma unroll
    for (int i = 0; i < 8; ++i) o.u[i] = f2bf(W[(size_t)(k0+i)*1024 + c]);
    *(s8v*)(wp + (size_t)t*8) = o.v;
}

// ---------------- mega-prep: packs + zeroing + lin1(bf16) + a1 -------------
__global__ __launch_bounds__(256) void prep_kernel(
        const float* __restrict__ l2w, unsigned short* __restrict__ w2p,
        const float* __restrict__ wf1w, unsigned short* __restrict__ wf1,
        const float* __restrict__ wf2w, unsigned short* __restrict__ wf2,
        const float* __restrict__ wf3w, unsigned short* __restrict__ wf3,
        int* __restrict__ fill, int* __restrict__ fill2,
        float* __restrict__ z, float* __restrict__ scal,
        const float* __restrict__ x, const float* __restrict__ l1w,
        const float* __restrict__ l1b, const float* __restrict__ u1,
        unsigned short* __restrict__ h1, float* __restrict__ a) {
    __shared__ float hsh[16][16];
    int b = blockIdx.x;
    int tid = threadIdx.x;
    if (b < 64)  { packw_lin_body(l2w, w2p, b*256 + tid); return; }
    b -= 64;
    if (b < 2)   { packw_feast_body<16,32>(wf1w, wf1, b*256 + tid); return; }
    b -= 2;
    if (b < 8)   { packw_feast_body<32,64>(wf2w, wf2, b*256 + tid); return; }
    b -= 8;
    if (b < 32)  { packw_feast_body<64,128>(wf3w, wf3, b*256 + tid); return; }
    b -= 32;
    if (b < 587) {
        int idx = b*256 + tid;
        if (idx < NN)            fill[idx] = 0;
        else if (idx < 2*NN)     fill2[idx - NN] = 0;
        else if (idx < 3*NN)     z[idx - 2*NN] = 0.f;
        else if (idx < 3*NN+16)  scal[idx - 3*NN] = 0.f;
        return;
    }
    b -= 587;                        // 0..3124 : lin1 + a1
    int n0 = b * 16;
    int node = n0 + (tid >> 4), col = tid & 15;
    float v = x[node*3+0]*l1w[col] + x[node*3+1]*l1w[16+col]
            + x[node*3+2]*l1w[32+col] + l1b[col];
    v = fmaxf(v, 0.f);
    h1[(size_t)node*16 + col] = f2bf(v);
    hsh[tid >> 4][col] = v;
    __syncthreads();
    if (tid < 128) {
        int t2 = tid >> 3, h = tid & 7;
        float acc = 0.f;
        #pragma unroll
        for (int k = 0; k < 16; ++k) acc += hsh[t2][k] * u1[k*8 + h];
        a[(size_t)(n0 + t2)*8 + h] = acc;
    }
}

// ---------------- CSR build ----------------
__global__ void hist_kernel(const int* __restrict__ dst, int* __restrict__ cnt) {
    int e = blockIdx.x * 256 + threadIdx.x;
    if (e < NE) atomicAdd(&cnt[dst[e]], 1);
}

__global__ void scan1_kernel(const int* __restrict__ cnt, int* __restrict__ rp,
                             int* __restrict__ bpart) {
    __shared__ int sh[256];
    int tid = threadIdx.x;
    int gid = blockIdx.x * 256 + tid;
    int v = (gid < NN) ? cnt[gid] : 0;
    sh[tid] = v;
    __syncthreads();
    for (int off = 1; off < 256; off <<= 1) {
        int t = (tid >= off) ? sh[tid - off] : 0;
        __syncthreads();
        sh[tid] += t;
        __syncthreads();
    }
    if (gid < NN) rp[gid] = sh[tid] - v;
    if (tid == 255) bpart[blockIdx.x] = sh[tid];
}

__global__ void scanfix_kernel(int* __restrict__ rp, const int* __restrict__ bpart,
                               int nblk) {
    __shared__ int sh[256];
    int tid = threadIdx.x;
    int bx = blockIdx.x;
    sh[tid] = (tid < bx && tid < nblk) ? bpart[tid] : 0;
    __syncthreads();
    for (int off = 128; off; off >>= 1) {
        if (tid < off) sh[tid] += sh[tid + off];
        __syncthreads();
    }
    int add = sh[0];
    int gid = bx * 256 + tid;
    if (gid < NN) rp[gid] += add;
    if (gid == 0) rp[NN] = NE;
}

__global__ void scatter_kernel(const int* __restrict__ src, const int* __restrict__ dst,
                               const int* __restrict__ rp, int* __restrict__ fill,
                               int* __restrict__ ssrc) {
    int e = blockIdx.x * 256 + threadIdx.x;
    if (e >= NE) return;
    int d = dst[e];
    int pos = rp[d] + atomicAdd(&fill[d], 1);
    ssrc[pos] = src[e];
}

// ---------------- fused q + agg ----------------
// One wave per dst. Per <=64-edge chunk: phase 1 = one edge per lane computes
// the 8-head softmax and stores q to this wave's LDS strip; phase 2 = gather
// loop over the chunk reading q from LDS. Same-wave LDS, no barriers needed.
template<int CIN>
__global__ __launch_bounds__(256) void agg_kernel(
        const unsigned short* __restrict__ hin, const float* __restrict__ a,
        const float* __restrict__ cbias,
        const int* __restrict__ rowptr, const int* __restrict__ ssrc,
        unsigned short* __restrict__ g) {
    constexpr int HPER = CIN / 8;
    constexpr int LG = (CIN == 16) ? 4 : (CIN == 32) ? 5 : 6;
    __shared__ float qsh[4][64][8];
    const int lane = threadIdx.x & 63;
    const int w = threadIdx.x >> 6;
    const int d = blockIdx.x * 4 + w;
    const int k = lane & (CIN - 1);
    const int hg = lane >> LG;
    float cc[8], ad[8];
    #pragma unroll
    for (int h = 0; h < 8; ++h) { cc[h] = cbias[h]; ad[h] = a[(size_t)d*8 + h]; }
    float m0 = cc[0];
    #pragma unroll
    for (int h = 1; h < 8; ++h) m0 = fmaxf(m0, cc[h]);
    float ssum = 0.f;
    #pragma unroll
    for (int h = 0; h < 8; ++h) ssum += __expf(cc[h] - m0);
    float sinv = 1.f / ssum;
    float xd = bf2f(hin[(size_t)d*CIN + k]);
    float acc[HPER];
    #pragma unroll
    for (int i = 0; i < HPER; ++i)
        acc[i] = __expf(cc[hg*HPER + i] - m0) * sinv * xd;
    const int j0 = rowptr[d], j1 = rowptr[d+1];
    for (int jb = j0; jb < j1; jb += 64) {
        int cnt = j1 - jb; if (cnt > 64) cnt = 64;
        if (lane < cnt) {                          // phase 1: q per edge
            int s = ssrc[jb + lane];
            const float4* as = (const float4*)(a + (size_t)s*8);
            float4 s0 = as[0], s1 = as[1];
            float lg[8] = { s0.x-ad[0]+cc[0], s0.y-ad[1]+cc[1],
                            s0.z-ad[2]+cc[2], s0.w-ad[3]+cc[3],
                            s1.x-ad[4]+cc[4], s1.y-ad[5]+cc[5],
                            s1.z-ad[6]+cc[6], s1.w-ad[7]+cc[7] };
            float m = lg[0];
            #pragma unroll
            for (int h = 1; h < 8; ++h) m = fmaxf(m, lg[h]);
            float sum = 0.f;
            #pragma unroll
            for (int h = 0; h < 8; ++h) { lg[h] = __expf(lg[h]-m); sum += lg[h]; }
            float inv = 1.f / sum;
            float4* qp = (float4*)&qsh[w][lane][0];
            qp[0] = make_float4(lg[0]*inv, lg[1]*inv, lg[2]*inv, lg[3]*inv);
            qp[1] = make_float4(lg[4]*inv, lg[5]*inv, lg[6]*inv, lg[7]*inv);
        }
        int je = jb + cnt;                          // phase 2: gather
        int j = jb;
        for (; j + 2 <= je; j += 2) {
            int s0 = ssrc[j], s1 = ssrc[j+1];
            float xv0 = bf2f(hin[(size_t)s0*CIN + k]);
            float xv1 = bf2f(hin[(size_t)s1*CIN + k]);
            float qv0[HPER], qv1[HPER];
            if constexpr (HPER == 2) {
                float2 t0 = *(const float2*)&qsh[w][j-jb][hg*2];
                float2 t1 = *(const float2*)&qsh[w][j+1-jb][hg*2];
                qv0[0]=t0.x; qv0[1]=t0.y; qv1[0]=t1.x; qv1[1]=t1.y;
            } else if constexpr (HPER == 4) {
                float4 t0 = *(const float4*)&qsh[w][j-jb][hg*4];
                float4 t1 = *(const float4*)&qsh[w][j+1-jb][hg*4];
                qv0[0]=t0.x; qv0[1]=t0.y; qv0[2]=t0.z; qv0[3]=t0.w;
                qv1[0]=t1.x; qv1[1]=t1.y; qv1[2]=t1.z; qv1[3]=t1.w;
            } else {
                float4 t0a = *(const float4*)&qsh[w][j-jb][0];
                float4 t0b = *(const float4*)&qsh[w][j-jb][4];
                float4 t1a = *(const float4*)&qsh[w][j+1-jb][0];
                float4 t1b = *(const float4*)&qsh[w][j+1-jb][4];
                qv0[0]=t0a.x; qv0[1]=t0a.y; qv0[2]=t0a.z; qv0[3]=t0a.w;
                qv0[4]=t0b.x; qv0[5]=t0b.y; qv0[6]=t0b.z; qv0[7]=t0b.w;
                qv1[0]=t1a.x; qv1[1]=t1a.y; qv1[2]=t1a.z; qv1[3]=t1a.w;
                qv1[4]=t1b.x; qv1[5]=t1b.y; qv1[6]=t1b.z; qv1[7]=t1b.w;
            }
            #pragma unroll
            for (int i = 0; i < HPER; ++i) acc[i] += qv0[i]*xv0 + qv1[i]*xv1;
        }
        if (j < je) {
            int s0 = ssrc[j];
            float xv0 = bf2f(hin[(size_t)s0*CIN + k]);
            #pragma unroll
            for (int i = 0; i < HPER; ++i)
                acc[i] += qsh[w][j-jb][hg*HPER + i] * xv0;
        }
    }
    #pragma unroll
    for (int i = 0; i < HPER; ++i)
        g[(size_t)d*(8*CIN) + (hg*HPER + i)*CIN + k] = f2bf(acc[i]);
}

// ---------------- feast GEMM (bf16 out, optional a-epilogue) ---------------
template<int K, int O, int CH, bool AEPI>
__global__ __launch_bounds__(256) void gemm_feast(
        const unsigned short* __restrict__ g, const unsigned short* __restrict__ wp,
        const int* __restrict__ rowptr, const float* __restrict__ b,
        unsigned short* __restrict__ hout,
        const float* __restrict__ unext, float* __restrict__ aout) {
    constexpr int NS = K / 32;
    constexpr int NCT = O / 16;
    __shared__ unsigned short bsh[CH*NS*64*8];
    const int l = threadIdx.x & 63;
    const int w = threadIdx.x >> 6;
    const int base = blockIdx.x * 64 + w * 16;
    int arow = base + (l & 15); if (arow >= NN) arow = NN - 1;
    const int koff = (l >> 4) * 8;
    s8v af[NS];
    #pragma unroll
    for (int s = 0; s < NS; ++s)
        af[s] = *(const s8v*)(g + (size_t)arow*K + s*32 + koff);
    float invc[4];
    #pragma unroll
    for (int r = 0; r < 4; ++r) {
        int n = base + (l >> 4)*4 + r; if (n >= NN) n = NN - 1;
        invc[r] = 1.f / (float)(rowptr[n+1] - rowptr[n] + 1);
    }
    float apart[4][8];
    if constexpr (AEPI) {
        #pragma unroll
        for (int r = 0; r < 4; ++r)
            #pragma unroll
            for (int h = 0; h < 8; ++h) apart[r][h] = 0.f;
    }
    #pragma unroll 1
    for (int ct0 = 0; ct0 < NCT; ct0 += CH) {
        __syncthreads();
        const int4* sp = (const int4*)(wp + (size_t)ct0*NS*512);
        int4* dp = (int4*)bsh;
        #pragma unroll 1
        for (int i = threadIdx.x; i < CH*NS*64; i += 256) dp[i] = sp[i];
        __syncthreads();
        #pragma unroll 1
        for (int cc = 0; cc < CH; ++cc) {
            f4v accA = {0.f,0.f,0.f,0.f}, accB = {0.f,0.f,0.f,0.f};
            #pragma unroll
            for (int s = 0; s < NS/2; ++s) {
                s8v bf = *(const s8v*)(bsh + ((size_t)(cc*NS + s)*64 + l)*8);
                accA = __builtin_amdgcn_mfma_f32_16x16x32_bf16(af[s], bf, accA, 0, 0, 0);
            }
            #pragma unroll
            for (int s = NS/2; s < NS; ++s) {
                s8v bf = *(const s8v*)(bsh + ((size_t)(cc*NS + s)*64 + l)*8);
                accB = __builtin_amdgcn_mfma_f32_16x16x32_bf16(af[s], bf, accB, 0, 0, 0);
            }
            int col = (ct0 + cc)*16 + (l & 15);
            float bb = b[col];
            float uv[8];
            if constexpr (AEPI) {
                #pragma unroll
                for (int h = 0; h < 8; ++h) uv[h] = unext[col*8 + h];
            }
            #pragma unroll
            for (int r = 0; r < 4; ++r) {
                int n = base + (l >> 4)*4 + r;
                float v = fmaxf((accA[r]+accB[r])*invc[r] + bb, 0.f);
                if constexpr (AEPI) {
                    #pragma unroll
                    for (int h = 0; h < 8; ++h) apart[r][h] += v * uv[h];
                }
                if (n < NN) hout[(size_t)n*O + col] = f2bf(v);
            }
        }
    }
    if constexpr (AEPI) {
        #pragma unroll
        for (int r = 0; r < 4; ++r)
            #pragma unroll
            for (int h = 0; h < 8; ++h) {
                float v = apart[r][h];
                v += __shfl_xor(v, 1, 64);
                v += __shfl_xor(v, 2, 64);
                v += __shfl_xor(v, 4, 64);
                v += __shfl_xor(v, 8, 64);
                if ((l & 15) == 0) {
                    int n = base + (l >> 4)*4 + r;
                    if (n < NN) aout[(size_t)n*8 + h] = v;
                }
            }
    }
}

// ---------------- lin23 split-ct z reduction ----------------
__global__ __launch_bounds__(256) void lin23z_kernel(
        const unsigned short* __restrict__ h4b, const unsigned short* __restrict__ w2p,
        const float* __restrict__ b2, const float* __restrict__ w3,
        float* __restrict__ z) {
    const int l = threadIdx.x & 63;
    const int w = threadIdx.x >> 6;
    const int ctg = blockIdx.y;
    const int rowbase = blockIdx.x * 256 + w * 64;
    const int koff = (l >> 4) * 8;
    s8v bf0[4], bf1[4], bf2[4], bf3[4];
    #pragma unroll
    for (int s = 0; s < 4; ++s) {
        bf0[s] = *(const s8v*)(w2p + ((size_t)((ctg*4+0)*4 + s)*64 + l)*8);
        bf1[s] = *(const s8v*)(w2p + ((size_t)((ctg*4+1)*4 + s)*64 + l)*8);
        bf2[s] = *(const s8v*)(w2p + ((size_t)((ctg*4+2)*4 + s)*64 + l)*8);
        bf3[s] = *(const s8v*)(w2p + ((size_t)((ctg*4+3)*4 + s)*64 + l)*8);
    }
    float w3c[4], b2c[4];
    #pragma unroll
    for (int c = 0; c < 4; ++c) {
        int col = (ctg*4 + c)*16 + (l & 15);
        w3c[c] = w3[col]; b2c[c] = b2[col];
    }
    #pragma unroll 1
    for (int t = 0; t < 4; ++t) {
        int base = rowbase + t*16;
        int arow = base + (l & 15); if (arow >= NN) arow = NN - 1;
        s8v af[4];
        #pragma unroll
        for (int s = 0; s < 4; ++s)
            af[s] = *(const s8v*)(h4b + (size_t)arow*128 + s*32 + koff);
        float zp0 = 0.f, zp1 = 0.f, zp2 = 0.f, zp3 = 0.f;
        #pragma unroll
        for (int c = 0; c < 4; ++c) {
            const s8v* bf = (c == 0) ? bf0 : (c == 1) ? bf1 : (c == 2) ? bf2 : bf3;
            f4v accA = {0.f,0.f,0.f,0.f}, accB = {0.f,0.f,0.f,0.f};
            accA = __builtin_amdgcn_mfma_f32_16x16x32_bf16(af[0], bf[0], accA, 0, 0, 0);
            accA = __builtin_amdgcn_mfma_f32_16x16x32_bf16(af[1], bf[1], accA, 0, 0, 0);
            accB = __builtin_amdgcn_mfma_f32_16x16x32_bf16(af[2], bf[2], accB, 0, 0, 0);
            accB = __builtin_amdgcn_mfma_f32_16x16x32_bf16(af[3], bf[3], accB, 0, 0, 0);
            zp0 += fmaxf(accA[0]+accB[0] + b2c[c], 0.f) * w3c[c];
            zp1 += fmaxf(accA[1]+accB[1] + b2c[c], 0.f) * w3c[c];
            zp2 += fmaxf(accA[2]+accB[2] + b2c[c], 0.f) * w3c[c];
            zp3 += fmaxf(accA[3]+accB[3] + b2c[c], 0.f) * w3c[c];
        }
        #pragma unroll
        for (int m = 1; m < 16; m <<= 1) {
            zp0 += __shfl_xor(zp0, m, 64);
            zp1 += __shfl_xor(zp1, m, 64);
            zp2 += __shfl_xor(zp2, m, 64);
            zp3 += __shfl_xor(zp3, m, 64);
        }
        if ((l & 15) == 0) {
            int r0 = base + (l >> 4) * 4;
            if (r0+0 < NN) atomicAdd(&z[r0+0], zp0);
            if (r0+1 < NN) atomicAdd(&z[r0+1], zp1);
            if (r0+2 < NN) atomicAdd(&z[r0+2], zp2);
            if (r0+3 < NN) atomicAdd(&z[r0+3], zp3);
        }
    }
}

// ---------------- finish: sigmoid + balanced-BCE loss ----------------
__global__ void finish_kernel(const float* __restrict__ labels,
                              const float* __restrict__ z,
                              const float* __restrict__ b3,
                              float* __restrict__ p,
                              float* __restrict__ scal,
                              float* __restrict__ out, int nblk) {
    __shared__ float sh0[256], sh1[256], sh2[256];
    int tid = threadIdx.x;
    int n = blockIdx.x * 256 + tid;
    float pos = 0.f, sp = 0.f, sn = 0.f;
    if (n < NN) {
        float pv = 1.f / (1.f + expf(-(z[n] + b3[0])));
        p[n] = pv;
        float yv = labels[n];
        if (yv == 1.0f) { pos = 1.f; sp = -fmaxf(logf(pv), -100.f); }
        else            { sn = -fmaxf(logf(1.f - pv), -100.f); }
    }
    sh0[tid] = pos; sh1[tid] = sp; sh2[tid] = sn;
    __syncthreads();
    for (int off = 128; off; off >>= 1) {
        if (tid < off) {
            sh0[tid] += sh0[tid+off];
            sh1[tid] += sh1[tid+off];
            sh2[tid] += sh2[tid+off];
        }
        __syncthreads();
    }
    if (tid == 0) {
        atomicAdd(&scal[0], sh0[0]);
        atomicAdd(&scal[1], sh1[0]);
        atomicAdd(&scal[2], sh2[0]);
        __threadfence();
        int t = atomicAdd((int*)&scal[4], 1);
        if (t == nblk - 1) {
            float posT = atomicAdd(&scal[0], 0.f);
            float spT  = atomicAdd(&scal[1], 0.f);
            float snT  = atomicAdd(&scal[2], 0.f);
            out[0] = spT / (2.f*posT) + snT / (2.f*((float)NN - posT));
        }
    }
}

// ---------------- launch ----------------
extern "C" void kernel_launch(void* const* d_in, const int* in_sizes, int n_in,
                              void* d_out, int out_size, void* d_ws, size_t ws_size,
                              hipStream_t stream) {
    (void)in_sizes; (void)n_in; (void)out_size; (void)ws_size;
    const float* x   = (const float*)d_in[0];
    const int*   ei  = (const int*)d_in[1];
    const float* labels = (const float*)d_in[2];
    const float* l1w = (const float*)d_in[3];
    const float* l1b = (const float*)d_in[4];
    const float* cw[3] = {(const float*)d_in[5], (const float*)d_in[9],  (const float*)d_in[13]};
    const float* cu[3] = {(const float*)d_in[6], (const float*)d_in[10], (const float*)d_in[14]};
    const float* cc[3] = {(const float*)d_in[7], (const float*)d_in[11], (const float*)d_in[15]};
    const float* cb[3] = {(const float*)d_in[8], (const float*)d_in[12], (const float*)d_in[16]};
    const float* l2w = (const float*)d_in[17];
    const float* l2b = (const float*)d_in[18];
    const float* l3w = (const float*)d_in[19];
    const float* l3b = (const float*)d_in[20];
    const int* srcp = ei;
    const int* dstp = ei + NE;
    float* out = (float*)d_out;

    // ---- workspace (float units, 64B aligned) ----
    float* ws = (float*)d_ws;
    size_t off = 0;
    auto alloc = [&](size_t n) { float* p = ws + off; off += (n + 15) & ~(size_t)15; return p; };
    unsigned short* hA = (unsigned short*)alloc((size_t)NN*32);   // bf16: h1(N,16) then h3(N,64)
    unsigned short* hB = (unsigned short*)alloc((size_t)NN*64);   // bf16: h2(N,32) then h4(N,128)
    float* a  = alloc((size_t)NN*8);
    unsigned short* g   = (unsigned short*)alloc((size_t)NN*256);
    unsigned short* w2p = (unsigned short*)alloc(65536);
    unsigned short* wf1 = (unsigned short*)alloc(2048);
    unsigned short* wf2 = (unsigned short*)alloc(8192);
    unsigned short* wf3 = (unsigned short*)alloc(32768);
    float* z    = alloc(NN);
    float* scal = alloc(16);
    int* rowptr = (int*)alloc(50016);
    int* fill   = (int*)alloc(NN);
    int* fill2  = (int*)alloc(NN);
    int* ssrc   = (int*)alloc(NE);
    int* bpart  = (int*)alloc(256);

    const int SCAN_BLKS = (NN + 255) / 256;           // 196
    const int GB = (NN + 63) / 64;                    // 782
    const int PREP_BLKS = 106 + 587 + NN/16;          // 3818

    // ---- prep + CSR build ----
    prep_kernel<<<PREP_BLKS, 256, 0, stream>>>(l2w, w2p, cw[0], wf1, cw[1], wf2,
                                               cw[2], wf3, fill, fill2, z, scal,
                                               x, l1w, l1b, cu[0], hA, a);
    hist_kernel<<<(NE+255)/256, 256, 0, stream>>>(dstp, fill);
    scan1_kernel<<<SCAN_BLKS, 256, 0, stream>>>(fill, rowptr, bpart);
    scanfix_kernel<<<SCAN_BLKS, 256, 0, stream>>>(rowptr, bpart, SCAN_BLKS);
    scatter_kernel<<<(NE+255)/256, 256, 0, stream>>>(srcp, dstp, rowptr, fill2, ssrc);

    // ---- conv1: cin=16 -> O=32 (hA -> hB); epilogue a2 ----
    agg_kernel<16><<<NN/4, 256, 0, stream>>>(hA, a, cc[0], rowptr, ssrc, g);
    gemm_feast<128,32,2,true><<<GB, 256, 0, stream>>>(g, wf1, rowptr, cb[0], hB, cu[1], a);

    // ---- conv2: cin=32 -> O=64 (hB -> hA); epilogue a3 ----
    agg_kernel<32><<<NN/4, 256, 0, stream>>>(hB, a, cc[1], rowptr, ssrc, g);
    gemm_feast<256,64,4,true><<<GB, 256, 0, stream>>>(g, wf2, rowptr, cb[1], hA, cu[2], a);

    // ---- conv3: cin=64 -> O=128 (hA -> hB) ----
    agg_kernel<64><<<NN/4, 256, 0, stream>>>(hA, a, cc[2], rowptr, ssrc, g);
    gemm_feast<512,128,2,false><<<GB, 256, 0, stream>>>(g, wf3, rowptr, cb[2], hB, nullptr, nullptr);

    // ---- lin2+lin3 z reduction, then sigmoid+loss ----
    lin23z_kernel<<<dim3((NN+255)/256, 16), 256, 0, stream>>>(hB, w2p, l2b, l3w, z);
    finish_kernel<<<SCAN_BLKS, 256, 0, stream>>>(labels, z, l3b, out + 1, scal, out, SCAN_BLKS);
}